// Round 6
// baseline (210.671 us; speedup 1.0000x reference)
//
#include <hip/hip_runtime.h>
#include <math.h>

constexpr int C  = 128;
constexpr int H  = 128;
constexpr int Wd = 128;
constexpr int HW = H * Wd;
constexpr int LH = 64, LW = 64;

constexpr int KRW = 130;                // k/v row stride: 2 left-pad zero cols
constexpr int KPLANE = 132 * KRW;       // 2 top + 128 + 2 bottom rows
constexpr int QRW = 129;                // q row stride: 1 left-pad zero col
constexpr int QPLANE = 130 * QRW;       // 1 top + 128 + 1 bottom rows
constexpr int KSZ = 2 * C * KPLANE;     // 4,392,960 floats
constexpr int QSZ = 2 * C * QPLANE;     // 4,293,120 floats
// ws: 2*KSZ + QSZ + 4 = 13,079,044 floats = 52.32 MB (proven safe in R5)

struct __attribute__((packed, aligned(4))) f4u { float x, y, z, w; };

__device__ __forceinline__ float sel4(const f4u& v, int i) {
  return i == 0 ? v.x : (i == 1 ? v.y : (i == 2 ? v.z : v.w));
}

// ---------------------------------------------------------------------------
// Kernel 1a (k/v dwconv only): thread = (n,c,y,4px). Lean: ~35 VGPR target
// (<=64 bin -> 8 waves/SIMD). Incremental row accumulation, branch-free.
// ---------------------------------------------------------------------------
__global__ __launch_bounds__(256, 8) void k_kv(
    const float* __restrict__ hr,
    const float* __restrict__ wk, const float* __restrict__ bk,
    const float* __restrict__ wv, const float* __restrict__ bv,
    float* __restrict__ kpad, float* __restrict__ vpad)
{
  const int t  = blockIdx.x * 256 + threadIdx.x;
  const int x4 = t & 31;
  const int y  = (t >> 5) & 127;
  const int nc = t >> 12;              // uniform within a block
  const int x  = x4 * 4;
  const int c  = nc & (C - 1);

  const float* hp = hr + nc * HW;
  const float* wkc = wk + c * 9;       // uniform -> s_load
  const float* wvc = wv + c * 9;
  float ko[4], vo[4];
#pragma unroll
  for (int j = 0; j < 4; j++) { ko[j] = bk[c]; vo[j] = bv[c]; }

#pragma unroll
  for (int r = 0; r < 3; r++) {
    const int gy = y + r - 1;
    const bool okr = (gy >= 0) && (gy < H);
    const int gyc = min(max(gy, 0), H - 1);
    const float* rp = hp + gyc * Wd;
    const f4u m = *(const f4u*)(rp + x);
    const float lft = rp[max(x - 1, 0)];
    const float rgt = rp[min(x + 4, Wd - 1)];
    float h[6];
    h[0] = (okr && x > 0) ? lft : 0.f;
    h[1] = okr ? m.x : 0.f;
    h[2] = okr ? m.y : 0.f;
    h[3] = okr ? m.z : 0.f;
    h[4] = okr ? m.w : 0.f;
    h[5] = (okr && x + 4 < Wd) ? rgt : 0.f;
#pragma unroll
    for (int dj = 0; dj < 3; dj++) {
      const float a = wkc[r * 3 + dj], b = wvc[r * 3 + dj];
#pragma unroll
      for (int j = 0; j < 4; j++) {
        ko[j] += a * h[j + dj];
        vo[j] += b * h[j + dj];
      }
    }
  }

  float* kr = kpad + nc * KPLANE + (y + 2) * KRW + 2 + x;
  float* vr = vpad + nc * KPLANE + (y + 2) * KRW + 2 + x;
  *(float2*)(kr) = make_float2(ko[0], ko[1]);
  *(float2*)(kr + 2) = make_float2(ko[2], ko[3]);
  *(float2*)(vr) = make_float2(vo[0], vo[1]);
  *(float2*)(vr + 2) = make_float2(vo[2], vo[3]);

  // pad zeroing (ws poisoned each call)
  if (x4 == 0) { kr[-2] = 0.f; kr[-1] = 0.f; vr[-2] = 0.f; vr[-1] = 0.f; }
  if (y == 0) {
    float* kz = kpad + nc * KPLANE;
    float* vz = vpad + nc * KPLANE;
#pragma unroll
    for (int j = 0; j < 4; j++) {
      kz[2 + x + j] = 0.f;        kz[KRW + 2 + x + j] = 0.f;
      vz[2 + x + j] = 0.f;        vz[KRW + 2 + x + j] = 0.f;
    }
    if (x4 == 0) {
      kz[0] = kz[1] = kz[KRW] = kz[KRW + 1] = 0.f;
      vz[0] = vz[1] = vz[KRW] = vz[KRW + 1] = 0.f;
    }
  }
  if (y == 127) {
    float* kz = kpad + nc * KPLANE + 130 * KRW;
    float* vz = vpad + nc * KPLANE + 130 * KRW;
#pragma unroll
    for (int j = 0; j < 4; j++) {
      kz[2 + x + j] = 0.f;        kz[KRW + 2 + x + j] = 0.f;
      vz[2 + x + j] = 0.f;        vz[KRW + 2 + x + j] = 0.f;
    }
    if (x4 == 0) {
      kz[0] = kz[1] = kz[KRW] = kz[KRW + 1] = 0.f;
      vz[0] = vz[1] = vz[KRW] = vz[KRW + 1] = 0.f;
    }
  }
}

// ---------------------------------------------------------------------------
// Kernel 1b (bilinear lr_up + q dwconv): thread = (n,c,y,4px). Row-incremental
// accumulation keeps live registers small (<=64 bin target).
// ---------------------------------------------------------------------------
__global__ __launch_bounds__(256, 8) void k_q(
    const float* __restrict__ lr,
    const float* __restrict__ wq, const float* __restrict__ bq,
    float* __restrict__ lrup_out, float* __restrict__ qpad,
    float* __restrict__ gap)
{
  const int t  = blockIdx.x * 256 + threadIdx.x;
  const int x4 = t & 31;
  const int y  = (t >> 5) & 127;
  const int nc = t >> 12;
  const int x  = x4 * 4;
  const int c  = nc & (C - 1);

  const float scale = 63.0f / 127.0f;
  const float* lp = lr + nc * (LH * LW);
  const float* wqc = wq + c * 9;       // uniform -> s_load
  float qo[4];
#pragma unroll
  for (int j = 0; j < 4; j++) qo[j] = bq[c];
  float up[4];

#pragma unroll
  for (int r = 0; r < 3; r++) {
    const int gy = y + r - 1;
    const bool okr = (gy >= 0) && (gy < H);
    const int gyc = min(max(gy, 0), H - 1);
    const float fy = gyc * scale;
    const int y0 = (int)fy;
    const float wy = fy - y0;
    const int y1 = min(y0 + 1, LH - 1);
    const int gx0 = max(x - 1, 0);
    const int xb = min((int)(gx0 * scale), LW - 4);
    const f4u r0 = *(const f4u*)(lp + y0 * LW + xb);
    const f4u r1 = *(const f4u*)(lp + y1 * LW + xb);
    float row[6];
#pragma unroll
    for (int j = 0; j < 6; j++) {
      const int gx = x + j - 1;
      const bool okc = (gx >= 0) && (gx < Wd);
      const int gxc = min(max(gx, 0), Wd - 1);
      const float fx = gxc * scale;
      const int x0 = (int)fx;
      const float wx = fx - x0;
      const int i0 = x0 - xb;                      // in [0,3] for this grid
      const int i1 = min(x0 + 1, LW - 1) - xb;     // in [0,3] for this grid
      const float p00 = sel4(r0, i0), p01 = sel4(r0, i1);
      const float p10 = sel4(r1, i0), p11 = sel4(r1, i1);
      const float t0 = p00 + (p01 - p00) * wx;
      const float t1 = p10 + (p11 - p10) * wx;
      row[j] = (okr && okc) ? (t0 + (t1 - t0) * wy) : 0.f;
    }
#pragma unroll
    for (int dj = 0; dj < 3; dj++) {
      const float a = wqc[r * 3 + dj];
#pragma unroll
      for (int j = 0; j < 4; j++) qo[j] += a * row[j + dj];
    }
    if (r == 1) { up[0] = row[1]; up[1] = row[2]; up[2] = row[3]; up[3] = row[4]; }
  }

  *(float4*)(lrup_out + nc * HW + y * Wd + x) =
      make_float4(up[0], up[1], up[2], up[3]);
  float* qr = qpad + nc * QPLANE + (y + 1) * QRW + 1 + x;
  qr[0] = qo[0]; qr[1] = qo[1]; qr[2] = qo[2]; qr[3] = qo[3];

  if (x4 == 0) qr[-1] = 0.f;
  if (y == 0) {
    float* qz = qpad + nc * QPLANE;
#pragma unroll
    for (int j = 0; j < 4; j++) qz[1 + x + j] = 0.f;
    if (x4 == 0) qz[0] = 0.f;
  }
  if (y == 127) {
    float* qz = qpad + nc * QPLANE + 129 * QRW;
#pragma unroll
    for (int j = 0; j < 4; j++) qz[1 + x + j] = 0.f;
    if (x4 == 0) qz[0] = 0.f;
  }
  if (t == 0) { gap[0] = 0.f; gap[1] = 0.f; gap[2] = 0.f; gap[3] = 0.f; }
}

// ---------------------------------------------------------------------------
// Kernel 2 (attention + gating fused). Same proven k-pass as R5; NEW: only
// 2 barriers — after the cross-wave reduce, EVERY thread reads the 27 reduced
// LDS rows and computes softmax + sigmoids redundantly in-register (no
// 64-of-512 idle phase, no LDS write-back, no 3rd barrier). __expf/rcp.
// ---------------------------------------------------------------------------
__global__ __launch_bounds__(512) void k_attn(
    const float* __restrict__ qpad, const float* __restrict__ kpad,
    const float* __restrict__ vpad, const float* __restrict__ wa,
    const float* __restrict__ ba, float* __restrict__ outb)
{
  __shared__ float red[25 * 512];   // 51.2 KB
  __shared__ float dsh[2 * 512];    // 4 KB

  const int tid = threadIdx.x;
  const int px = tid & 63;
  const int cgu = __builtin_amdgcn_readfirstlane(tid >> 6);  // wave-uniform
  const int x = blockIdx.x * 64 + px;
  const int y = blockIdx.y;
  const int n = blockIdx.z;
  const int c0 = n * C + cgu * 16;

  const float* kb = kpad + c0 * KPLANE + y * KRW + x;  // plane row y = tap dy-2
  const float* qb = qpad + c0 * QPLANE + y * QRW + x;  // plane row y = tap dy-1

  float sim[25];
#pragma unroll
  for (int k = 0; k < 25; k++) sim[k] = 0.f;
  float d0a = 0.f, d1a = 0.f;

#pragma unroll 4
  for (int ci = 0; ci < 16; ci++) {
    const float* kp = kb + ci * KPLANE;
    const float* qp = qb + ci * QPLANE;

    const f4u q0 = *(const f4u*)(qp);            // dx -1..+2 (use .x,.y,.z)
    const f4u q1 = *(const f4u*)(qp + QRW);
    const f4u q2 = *(const f4u*)(qp + 2 * QRW);

    const f4u a0 = *(const f4u*)(kp);            // dx -2..+1
    const f4u a1 = *(const f4u*)(kp + KRW);
    const f4u a2 = *(const f4u*)(kp + 2 * KRW);
    const f4u a3 = *(const f4u*)(kp + 3 * KRW);
    const f4u a4 = *(const f4u*)(kp + 4 * KRW);
    const float b0 = kp[4];                      // dx +2
    const float b1 = kp[KRW + 4];
    const float b2 = kp[2 * KRW + 4];
    const float b3 = kp[3 * KRW + 4];
    const float b4 = kp[4 * KRW + 4];

    const float qv = q1.y;                       // q center
    sim[0]  += qv * a0.x; sim[1]  += qv * a0.y; sim[2]  += qv * a0.z;
    sim[3]  += qv * a0.w; sim[4]  += qv * b0;
    sim[5]  += qv * a1.x; sim[6]  += qv * a1.y; sim[7]  += qv * a1.z;
    sim[8]  += qv * a1.w; sim[9]  += qv * b1;
    sim[10] += qv * a2.x; sim[11] += qv * a2.y; sim[12] += qv * a2.z;
    sim[13] += qv * a2.w; sim[14] += qv * b2;
    sim[15] += qv * a3.x; sim[16] += qv * a3.y; sim[17] += qv * a3.z;
    sim[18] += qv * a3.w; sim[19] += qv * b3;
    sim[20] += qv * a4.x; sim[21] += qv * a4.y; sim[22] += qv * a4.z;
    sim[23] += qv * a4.w; sim[24] += qv * b4;

    const float q3[9] = {q0.x, q0.y, q0.z, q1.x, q1.y, q1.z, q2.x, q2.y, q2.z};
    const float k3[9] = {a1.y, a1.z, a1.w, a2.y, a2.z, a2.w, a3.y, a3.z, a3.w};
    const int c = cgu * 16 + ci;                 // scalar -> s_load weights
    const float* w0q = wa + c * 9;
    const float* w1q = wa + 2304 + c * 9;
    const float* w0k = wa + (C + c) * 9;
    const float* w1k = wa + 2304 + (C + c) * 9;
#pragma unroll
    for (int tp = 0; tp < 9; tp++) {
      d0a += w0q[tp] * q3[tp] + w0k[tp] * k3[tp];
      d1a += w1q[tp] * q3[tp] + w1k[tp] * k3[tp];
    }
  }

  // stash partials
#pragma unroll
  for (int k = 0; k < 25; k++) red[k * 512 + tid] = sim[k];
  dsh[tid] = d0a;
  dsh[512 + tid] = d1a;
  __syncthreads();

  // cross-wave reduce; slots 25,26 carry the gating sums
  for (int k = cgu; k < 27; k += 8) {
    if (k < 25) {
      float s = 0.f;
#pragma unroll
      for (int g = 0; g < 8; g++) s += red[k * 512 + g * 64 + px];
      red[k * 512 + px] = s;
    } else if (k == 25) {
      float s = 0.f;
#pragma unroll
      for (int g = 0; g < 8; g++) s += dsh[g * 64 + px];
      dsh[px] = s;
    } else {
      float s = 0.f;
#pragma unroll
      for (int g = 0; g < 8; g++) s += dsh[512 + g * 64 + px];
      dsh[512 + px] = s;
    }
  }
  __syncthreads();

  // every thread: read reduced rows, softmax + sigmoid in-register
  float w[25];
  float m = -1e30f;
#pragma unroll
  for (int k = 0; k < 25; k++) { w[k] = red[k * 512 + px]; m = fmaxf(m, w[k]); }
  float tot = 0.f;
#pragma unroll
  for (int k = 0; k < 25; k++) { const float e = __expf(w[k] - m); w[k] = e; tot += e; }
  const float inv = __builtin_amdgcn_rcpf(tot);
#pragma unroll
  for (int k = 0; k < 25; k++) w[k] *= inv;
  const float g0 = __builtin_amdgcn_rcpf(1.f + __expf(-(dsh[px] + ba[0])));
  const float g1 = __builtin_amdgcn_rcpf(1.f + __expf(-(dsh[512 + px] + ba[1])));

  // value pass + epilogue
  const float* vb = vpad + c0 * KPLANE + y * KRW + x;
  float* op = outb + c0 * HW + y * Wd + x;
#pragma unroll 4
  for (int ci = 0; ci < 16; ci++) {
    const float* vp = vb + ci * KPLANE;
    const f4u a0 = *(const f4u*)(vp);
    const f4u a1 = *(const f4u*)(vp + KRW);
    const f4u a2 = *(const f4u*)(vp + 2 * KRW);
    const f4u a3 = *(const f4u*)(vp + 3 * KRW);
    const f4u a4 = *(const f4u*)(vp + 4 * KRW);
    const float b0 = vp[4];
    const float b1 = vp[KRW + 4];
    const float b2 = vp[2 * KRW + 4];
    const float b3 = vp[3 * KRW + 4];
    const float b4 = vp[4 * KRW + 4];

    float acc;
    acc  = w[0]  * a0.x + w[1]  * a0.y + w[2]  * a0.z + w[3]  * a0.w + w[4]  * b0;
    acc += w[5]  * a1.x + w[6]  * a1.y + w[7]  * a1.z + w[8]  * a1.w + w[9]  * b1;
    acc += w[10] * a2.x + w[11] * a2.y + w[12] * a2.z + w[13] * a2.w + w[14] * b2;
    acc += w[15] * a3.x + w[16] * a3.y + w[17] * a3.z + w[18] * a3.w + w[19] * b3;
    acc += w[20] * a4.x + w[21] * a4.y + w[22] * a4.z + w[23] * a4.w + w[24] * b4;
    const float vc = a2.z;                       // center tap (dy=0,dx=0)
    op[ci * HW] = op[ci * HW] + g0 * acc + g1 * vc;   // op holds lr_up
  }
}

// ---------------------------------------------------------------------------
extern "C" void kernel_launch(void* const* d_in, const int* in_sizes, int n_in,
                              void* d_out, int out_size, void* d_ws,
                              size_t ws_size, hipStream_t stream)
{
  const float* hr = (const float*)d_in[0];
  const float* lr = (const float*)d_in[1];
  const float* wq = (const float*)d_in[2];
  const float* bq = (const float*)d_in[3];
  const float* wk = (const float*)d_in[4];
  const float* bk = (const float*)d_in[5];
  const float* wv = (const float*)d_in[6];
  const float* bv = (const float*)d_in[7];
  const float* wa = (const float*)d_in[8];
  const float* ba = (const float*)d_in[9];

  float* out = (float*)d_out;
  float* ws  = (float*)d_ws;

  // layout: kpad | vpad | qpad | gap(4)  = 52.32 MB (identical to R5)
  float* kpad = ws;
  float* vpad = kpad + KSZ;
  float* qpad = vpad + KSZ;
  float* gapb = qpad + QSZ;

  k_kv<<<dim3(4096), dim3(256), 0, stream>>>(hr, wk, bk, wv, bv, kpad, vpad);
  k_q<<<dim3(4096), dim3(256), 0, stream>>>(lr, wq, bq, out, qpad, gapb);
  k_attn<<<dim3(2, 128, 2), dim3(512), 0, stream>>>(
      qpad, kpad, vpad, wa, ba, out);
}

// Round 7
// 179.285 us; speedup vs baseline: 1.1751x; 1.1751x over previous
//
#include <hip/hip_runtime.h>
#include <hip/hip_fp16.h>
#include <math.h>

constexpr int C  = 128;
constexpr int H  = 128;
constexpr int Wd = 128;
constexpr int HW = H * Wd;
constexpr int LH = 64, LW = 64;
constexpr int CP = 64;                  // channel PAIRS per image (half2-packed)

constexpr int KRW = 130;                // k/v row stride (half2 elems), 2 left pads
constexpr int KPLANE = 132 * KRW;       // 2 top + 128 + 2 bottom rows = 17160
constexpr int QRW = 129;                // q row stride, 1 left pad
constexpr int QPLANE = 130 * QRW;       // 1 top + 128 + 1 bottom rows = 16770
constexpr int KSZ = 2 * CP * KPLANE;    // 2,196,480 half2
constexpr int QSZ = 2 * CP * QPLANE;    // 2,146,560 half2
constexpr int LSZ = 2 * CP * HW;        // 2,097,152 half2
// ws: 2*KSZ + QSZ + 256 + LSZ + 4 = 8,636,932 * 4 B = 34.5 MB (< proven 50)

typedef __half2 h2;
struct __attribute__((packed, aligned(4)))  f4u { float x, y, z, w; };
struct __attribute__((packed, aligned(4)))  f4h { h2 a, b, c, d; };
struct __attribute__((packed, aligned(8)))  h2x2 { h2 a, b; };
struct __attribute__((packed, aligned(16))) h4 { h2 a, b, c, d; };

__device__ __forceinline__ float sel4(const f4u& v, int i) {
  return i == 0 ? v.x : (i == 1 ? v.y : (i == 2 ? v.z : v.w));
}

// ---------------------------------------------------------------------------
// Kernel 1 (pre, fused): thread = (n, cp, y, 4px) computing BOTH channels of
// pair cp. dwconv k/v from hr; bilinear lr_up + dwconv q from lr. All outputs
// half2 channel-pair packed. Branch-free math; pads zeroed by edge threads.
// grid 2048 x 256.
// ---------------------------------------------------------------------------
__global__ __launch_bounds__(256) void k_pre(
    const float* __restrict__ hr, const float* __restrict__ lr,
    const float* __restrict__ wq, const float* __restrict__ bq,
    const float* __restrict__ wk, const float* __restrict__ bk,
    const float* __restrict__ wv, const float* __restrict__ bv,
    h2* __restrict__ qpad, h2* __restrict__ kpad, h2* __restrict__ vpad,
    h2* __restrict__ lrup, h2* __restrict__ zgapA, h2* __restrict__ zgapB)
{
  const int t   = blockIdx.x * 256 + threadIdx.x;
  const int x4  = t & 31;
  const int y   = (t >> 5) & 127;
  const int ncp = t >> 12;             // n*CP+cp, uniform per block (4096/blk grp)
  const int x   = x4 * 4;
  const int cp  = ncp & (CP - 1);
  const int n   = ncp >> 6;
  const int c0  = cp * 2;
  const h2 hz   = __floats2half2_rn(0.f, 0.f);

  // ---- phase A: k,v dwconv for both channels ----
  float ko[2][4], vo[2][4];
#pragma unroll
  for (int cc = 0; cc < 2; cc++) {
    const int c = c0 + cc;
    const float* hp = hr + (n * C + c) * HW;
    const float* wkc = wk + c * 9;     // uniform -> s_load
    const float* wvc = wv + c * 9;
    const float bkc = bk[c], bvc = bv[c];
#pragma unroll
    for (int j = 0; j < 4; j++) { ko[cc][j] = bkc; vo[cc][j] = bvc; }
#pragma unroll
    for (int r = 0; r < 3; r++) {
      const int gy = y + r - 1;
      const bool okr = (gy >= 0) && (gy < H);
      const int gyc = min(max(gy, 0), H - 1);
      const float* rp = hp + gyc * Wd;
      const f4u m = *(const f4u*)(rp + x);
      const float lft = rp[max(x - 1, 0)];
      const float rgt = rp[min(x + 4, Wd - 1)];
      float h[6];
      h[0] = (okr && x > 0) ? lft : 0.f;
      h[1] = okr ? m.x : 0.f;  h[2] = okr ? m.y : 0.f;
      h[3] = okr ? m.z : 0.f;  h[4] = okr ? m.w : 0.f;
      h[5] = (okr && x + 4 < Wd) ? rgt : 0.f;
#pragma unroll
      for (int dj = 0; dj < 3; dj++) {
        const float a = wkc[r * 3 + dj], b = wvc[r * 3 + dj];
#pragma unroll
        for (int j = 0; j < 4; j++) {
          ko[cc][j] += a * h[j + dj];
          vo[cc][j] += b * h[j + dj];
        }
      }
    }
  }

  h2* kr = kpad + ncp * KPLANE + (y + 2) * KRW + 2 + x;
  h2* vr = vpad + ncp * KPLANE + (y + 2) * KRW + 2 + x;
  {
    h2x2 k01; k01.a = __floats2half2_rn(ko[0][0], ko[1][0]);
              k01.b = __floats2half2_rn(ko[0][1], ko[1][1]);
    h2x2 k23; k23.a = __floats2half2_rn(ko[0][2], ko[1][2]);
              k23.b = __floats2half2_rn(ko[0][3], ko[1][3]);
    h2x2 v01; v01.a = __floats2half2_rn(vo[0][0], vo[1][0]);
              v01.b = __floats2half2_rn(vo[0][1], vo[1][1]);
    h2x2 v23; v23.a = __floats2half2_rn(vo[0][2], vo[1][2]);
              v23.b = __floats2half2_rn(vo[0][3], vo[1][3]);
    *(h2x2*)(kr) = k01; *(h2x2*)(kr + 2) = k23;
    *(h2x2*)(vr) = v01; *(h2x2*)(vr + 2) = v23;
  }

  // ---- phase B: bilinear lr_up + q dwconv for both channels ----
  const float scale = 63.0f / 127.0f;
  float qo[2][4], up[2][4];
#pragma unroll
  for (int cc = 0; cc < 2; cc++) {
    const int c = c0 + cc;
    const float* lp = lr + (n * C + c) * (LH * LW);
    const float* wqc = wq + c * 9;     // uniform -> s_load
    const float bqc = bq[c];
#pragma unroll
    for (int j = 0; j < 4; j++) qo[cc][j] = bqc;
#pragma unroll
    for (int r = 0; r < 3; r++) {
      const int gy = y + r - 1;
      const bool okr = (gy >= 0) && (gy < H);
      const int gyc = min(max(gy, 0), H - 1);
      const float fy = gyc * scale;
      const int y0 = (int)fy;
      const float wy = fy - y0;
      const int y1 = min(y0 + 1, LH - 1);
      const int gx0 = max(x - 1, 0);
      const int xb = min((int)(gx0 * scale), LW - 4);
      const f4u r0 = *(const f4u*)(lp + y0 * LW + xb);
      const f4u r1 = *(const f4u*)(lp + y1 * LW + xb);
      float row[6];
#pragma unroll
      for (int j = 0; j < 6; j++) {
        const int gx = x + j - 1;
        const bool okc = (gx >= 0) && (gx < Wd);
        const int gxc = min(max(gx, 0), Wd - 1);
        const float fx = gxc * scale;
        const int x0 = (int)fx;
        const float wx = fx - x0;
        const int i0 = x0 - xb;
        const int i1 = min(x0 + 1, LW - 1) - xb;
        const float p00 = sel4(r0, i0), p01 = sel4(r0, i1);
        const float p10 = sel4(r1, i0), p11 = sel4(r1, i1);
        const float t0 = p00 + (p01 - p00) * wx;
        const float t1 = p10 + (p11 - p10) * wx;
        row[j] = (okr && okc) ? (t0 + (t1 - t0) * wy) : 0.f;
      }
#pragma unroll
      for (int dj = 0; dj < 3; dj++) {
        const float a = wqc[r * 3 + dj];
#pragma unroll
        for (int j = 0; j < 4; j++) qo[cc][j] += a * row[j + dj];
      }
      if (r == 1) {
        up[cc][0] = row[1]; up[cc][1] = row[2];
        up[cc][2] = row[3]; up[cc][3] = row[4];
      }
    }
  }

  {
    h4 U;
    U.a = __floats2half2_rn(up[0][0], up[1][0]);
    U.b = __floats2half2_rn(up[0][1], up[1][1]);
    U.c = __floats2half2_rn(up[0][2], up[1][2]);
    U.d = __floats2half2_rn(up[0][3], up[1][3]);
    *(h4*)(lrup + ncp * HW + y * Wd + x) = U;   // 16B aligned
  }
  h2* qr = qpad + ncp * QPLANE + (y + 1) * QRW + 1 + x;
#pragma unroll
  for (int j = 0; j < 4; j++) qr[j] = __floats2half2_rn(qo[0][j], qo[1][j]);

  // ---- pad zeroing (ws is poisoned every call) ----
  if (x4 == 0) {
    kr[-2] = hz; kr[-1] = hz; vr[-2] = hz; vr[-1] = hz; qr[-1] = hz;
  }
  if (y == 0) {    // top pad rows
    h2* kz = kpad + ncp * KPLANE;
    h2* vz = vpad + ncp * KPLANE;
    h2* qz = qpad + ncp * QPLANE;
#pragma unroll
    for (int j = 0; j < 4; j++) {
      kz[2 + x + j] = hz;  kz[KRW + 2 + x + j] = hz;
      vz[2 + x + j] = hz;  vz[KRW + 2 + x + j] = hz;
      qz[1 + x + j] = hz;
    }
    if (x4 == 0) {
      kz[0] = hz; kz[1] = hz; kz[KRW] = hz; kz[KRW + 1] = hz;
      vz[0] = hz; vz[1] = hz; vz[KRW] = hz; vz[KRW + 1] = hz;
      qz[0] = hz;
    }
  }
  if (y == 127) {  // bottom pad rows
    h2* kz = kpad + ncp * KPLANE + 130 * KRW;
    h2* vz = vpad + ncp * KPLANE + 130 * KRW;
    h2* qz = qpad + ncp * QPLANE + 129 * QRW;
#pragma unroll
    for (int j = 0; j < 4; j++) {
      kz[2 + x + j] = hz;  kz[KRW + 2 + x + j] = hz;
      vz[2 + x + j] = hz;  vz[KRW + 2 + x + j] = hz;
      qz[1 + x + j] = hz;
    }
    if (x4 == 0) {
      kz[0] = hz; kz[1] = hz; kz[KRW] = hz; kz[KRW + 1] = hz;
      vz[0] = hz; vz[1] = hz; vz[KRW] = hz; vz[KRW + 1] = hz;
      qz[0] = hz;
    }
  }
  if (t < 256) zgapA[t] = hz;   // zero gap between qpad and lrup
  if (t < 4)   zgapB[t] = hz;   // tail gap after lrup
}

#define SIMT(idx, reg) { const float2 t_ = __half22float2(reg); \
  sim[idx] += qc.x * t_.x + qc.y * t_.y; }
#define VT(idx, reg) { const float2 t_ = __half22float2(reg); \
  acc0 += w[idx] * t_.x; acc1 += w[idx] * t_.y; }

// ---------------------------------------------------------------------------
// Kernel 2 (attention + gating fused), half2 channel-pair packed.
// Block 512 = 8 waves; wave = 64 px x 8 pairs (16 ch). Same proven skeleton
// as R5/R6 (branch-free padded loads, LDS reduce, in-register softmax), but
// 8 channel iterations instead of 16 and d_out written ONCE (no RMW).
// grid (2,128,2) = 512 blocks.
// ---------------------------------------------------------------------------
__global__ __launch_bounds__(512) void k_attn(
    const h2* __restrict__ qpad, const h2* __restrict__ kpad,
    const h2* __restrict__ vpad, const h2* __restrict__ lrup,
    const float* __restrict__ wa, const float* __restrict__ ba,
    float* __restrict__ outb)
{
  __shared__ float red[25 * 512];   // 51.2 KB
  __shared__ float dsh[2 * 512];    // 4 KB

  const int tid = threadIdx.x;
  const int px = tid & 63;
  const int cgu = __builtin_amdgcn_readfirstlane(tid >> 6);  // wave-uniform
  const int x = blockIdx.x * 64 + px;
  const int y = blockIdx.y;
  const int n = blockIdx.z;
  const int cp0 = cgu * 8;

  float sim[25];
#pragma unroll
  for (int k = 0; k < 25; k++) sim[k] = 0.f;
  float d0a = 0.f, d1a = 0.f;

#pragma unroll 4
  for (int ci = 0; ci < 8; ci++) {
    const int cp = cp0 + ci;
    const h2* kp = kpad + (n * CP + cp) * KPLANE + y * KRW + x;
    const h2* qp = qpad + (n * CP + cp) * QPLANE + y * QRW + x;

    const f4h Q0 = *(const f4h*)(qp);            // dx -1..+2 (use a,b,c)
    const f4h Q1 = *(const f4h*)(qp + QRW);
    const f4h Q2 = *(const f4h*)(qp + 2 * QRW);
    const f4h A0 = *(const f4h*)(kp);            // dx -2..+1
    const f4h A1 = *(const f4h*)(kp + KRW);
    const f4h A2 = *(const f4h*)(kp + 2 * KRW);
    const f4h A3 = *(const f4h*)(kp + 3 * KRW);
    const f4h A4 = *(const f4h*)(kp + 4 * KRW);
    const h2 b0 = kp[4];                         // dx +2
    const h2 b1 = kp[KRW + 4];
    const h2 b2 = kp[2 * KRW + 4];
    const h2 b3 = kp[3 * KRW + 4];
    const h2 b4 = kp[4 * KRW + 4];

    const float2 qc = __half22float2(Q1.b);      // q center, both channels
    SIMT(0,  A0.a) SIMT(1,  A0.b) SIMT(2,  A0.c) SIMT(3,  A0.d) SIMT(4,  b0)
    SIMT(5,  A1.a) SIMT(6,  A1.b) SIMT(7,  A1.c) SIMT(8,  A1.d) SIMT(9,  b1)
    SIMT(10, A2.a) SIMT(11, A2.b) SIMT(12, A2.c) SIMT(13, A2.d) SIMT(14, b2)
    SIMT(15, A3.a) SIMT(16, A3.b) SIMT(17, A3.c) SIMT(18, A3.d) SIMT(19, b3)
    SIMT(20, A4.a) SIMT(21, A4.b) SIMT(22, A4.c) SIMT(23, A4.d) SIMT(24, b4)

    // gating conv partials, both channels, weights via wave-uniform s_load
    const float2 q3[9] = {
      __half22float2(Q0.a), __half22float2(Q0.b), __half22float2(Q0.c),
      __half22float2(Q1.a), __half22float2(Q1.b), __half22float2(Q1.c),
      __half22float2(Q2.a), __half22float2(Q2.b), __half22float2(Q2.c)};
    const float2 k3[9] = {
      __half22float2(A1.b), __half22float2(A1.c), __half22float2(A1.d),
      __half22float2(A2.b), __half22float2(A2.c), __half22float2(A2.d),
      __half22float2(A3.b), __half22float2(A3.c), __half22float2(A3.d)};
    const int c0 = 2 * cp;
    const float* w0q = wa + c0 * 9;              // [0..8]=ch c0, [9..17]=c0+1
    const float* w1q = wa + 2304 + c0 * 9;
    const float* w0k = wa + (C + c0) * 9;
    const float* w1k = wa + 2304 + (C + c0) * 9;
#pragma unroll
    for (int tp = 0; tp < 9; tp++) {
      d0a += w0q[tp] * q3[tp].x + w0q[9 + tp] * q3[tp].y
           + w0k[tp] * k3[tp].x + w0k[9 + tp] * k3[tp].y;
      d1a += w1q[tp] * q3[tp].x + w1q[9 + tp] * q3[tp].y
           + w1k[tp] * k3[tp].x + w1k[9 + tp] * k3[tp].y;
    }
  }

  // stash partials
#pragma unroll
  for (int k = 0; k < 25; k++) red[k * 512 + tid] = sim[k];
  dsh[tid] = d0a;
  dsh[512 + tid] = d1a;
  __syncthreads();

  // cross-wave reduce; slots 25,26 carry the gating sums
  for (int k = cgu; k < 27; k += 8) {
    if (k < 25) {
      float s = 0.f;
#pragma unroll
      for (int g = 0; g < 8; g++) s += red[k * 512 + g * 64 + px];
      red[k * 512 + px] = s;
    } else if (k == 25) {
      float s = 0.f;
#pragma unroll
      for (int g = 0; g < 8; g++) s += dsh[g * 64 + px];
      dsh[px] = s;
    } else {
      float s = 0.f;
#pragma unroll
      for (int g = 0; g < 8; g++) s += dsh[512 + g * 64 + px];
      dsh[512 + px] = s;
    }
  }
  __syncthreads();

  // every thread: softmax + sigmoids in-register (no 3rd barrier)
  float w[25];
  float m = -1e30f;
#pragma unroll
  for (int k = 0; k < 25; k++) { w[k] = red[k * 512 + px]; m = fmaxf(m, w[k]); }
  float tot = 0.f;
#pragma unroll
  for (int k = 0; k < 25; k++) { const float e = __expf(w[k] - m); w[k] = e; tot += e; }
  const float inv = __builtin_amdgcn_rcpf(tot);
#pragma unroll
  for (int k = 0; k < 25; k++) w[k] *= inv;
  const float g0 = __builtin_amdgcn_rcpf(1.f + __expf(-(dsh[px] + ba[0])));
  const float g1 = __builtin_amdgcn_rcpf(1.f + __expf(-(dsh[512 + px] + ba[1])));

  // value pass + epilogue (write d_out once; lr_up from packed ws buffer)
#pragma unroll 4
  for (int ci = 0; ci < 8; ci++) {
    const int cp = cp0 + ci;
    const h2* vp = vpad + (n * CP + cp) * KPLANE + y * KRW + x;
    const f4h B0 = *(const f4h*)(vp);
    const f4h B1 = *(const f4h*)(vp + KRW);
    const f4h B2 = *(const f4h*)(vp + 2 * KRW);
    const f4h B3 = *(const f4h*)(vp + 3 * KRW);
    const f4h B4 = *(const f4h*)(vp + 4 * KRW);
    const h2 c0h = vp[4];
    const h2 c1h = vp[KRW + 4];
    const h2 c2h = vp[2 * KRW + 4];
    const h2 c3h = vp[3 * KRW + 4];
    const h2 c4h = vp[4 * KRW + 4];

    float acc0 = 0.f, acc1 = 0.f;
    VT(0,  B0.a) VT(1,  B0.b) VT(2,  B0.c) VT(3,  B0.d) VT(4,  c0h)
    VT(5,  B1.a) VT(6,  B1.b) VT(7,  B1.c) VT(8,  B1.d) VT(9,  c1h)
    VT(10, B2.a) VT(11, B2.b) VT(12, B2.c) VT(13, B2.d) VT(14, c2h)
    VT(15, B3.a) VT(16, B3.b) VT(17, B3.c) VT(18, B3.d) VT(19, c3h)
    VT(20, B4.a) VT(21, B4.b) VT(22, B4.c) VT(23, B4.d) VT(24, c4h)
    const float2 vc = __half22float2(B2.c);      // center tap
    const float2 lu = __half22float2(lrup[(n * CP + cp) * HW + y * Wd + x]);

    float* op = outb + (n * C + 2 * cp) * HW + y * Wd + x;
    op[0]  = lu.x + g0 * acc0 + g1 * vc.x;
    op[HW] = lu.y + g0 * acc1 + g1 * vc.y;
  }
}

// ---------------------------------------------------------------------------
extern "C" void kernel_launch(void* const* d_in, const int* in_sizes, int n_in,
                              void* d_out, int out_size, void* d_ws,
                              size_t ws_size, hipStream_t stream)
{
  const float* hr = (const float*)d_in[0];
  const float* lr = (const float*)d_in[1];
  const float* wq = (const float*)d_in[2];
  const float* bq = (const float*)d_in[3];
  const float* wk = (const float*)d_in[4];
  const float* bk = (const float*)d_in[5];
  const float* wv = (const float*)d_in[6];
  const float* bv = (const float*)d_in[7];
  const float* wa = (const float*)d_in[8];
  const float* ba = (const float*)d_in[9];

  float* out = (float*)d_out;
  h2* ws2 = (h2*)d_ws;

  // layout (half2 elems): kpad | vpad | qpad | zgapA(256) | lrup | zgapB(4)
  // spill chain: k tail -> vpad top pad; v tail -> qpad top pad;
  // q tail -> zgapA (zero); lrup tail -> zgapB. Total 34.5 MB.
  h2* kpad  = ws2;
  h2* vpad  = kpad + KSZ;
  h2* qpad  = vpad + KSZ;
  h2* zgapA = qpad + QSZ;
  h2* lrupb = zgapA + 256;
  h2* zgapB = lrupb + LSZ;

  k_pre<<<dim3(2048), dim3(256), 0, stream>>>(
      hr, lr, wq, bq, wk, bk, wv, bv, qpad, kpad, vpad, lrupb, zgapA, zgapB);
  k_attn<<<dim3(2, 128, 2), dim3(512), 0, stream>>>(
      qpad, kpad, vpad, lrupb, wa, ba, out);
}

// Round 8
// 138.834 us; speedup vs baseline: 1.5174x; 1.2914x over previous
//
#include <hip/hip_runtime.h>
#include <hip/hip_fp16.h>
#include <math.h>

constexpr int C  = 128;
constexpr int H  = 128;
constexpr int Wd = 128;
constexpr int HW = H * Wd;
constexpr int LH = 64, LW = 64;
constexpr int CP = 64;                  // channel PAIRS per image (half2-packed)

constexpr int KRW = 130;                // k/v row stride (half2 elems), 2 left pads
constexpr int KPLANE = 132 * KRW;       // 2 top + 128 + 2 bottom rows = 17160
constexpr int QRW = 129;                // q row stride, 1 left pad
constexpr int QPLANE = 130 * QRW;       // 1 top + 128 + 1 bottom rows = 16770
constexpr int KSZ = 2 * CP * KPLANE;    // 2,196,480 half2
constexpr int QSZ = 2 * CP * QPLANE;    // 2,146,560 half2
constexpr int LSZ = 2 * CP * HW;        // 2,097,152 half2
// ws: 2*KSZ + QSZ + 256 + LSZ + 4 = 8,636,932 * 4 B = 34.5 MB (proven safe R7)

typedef __half2 h2;
struct __attribute__((packed, aligned(4)))  f4u { float x, y, z, w; };
struct __attribute__((packed, aligned(4)))  f4h { h2 a, b, c, d; };
struct __attribute__((packed, aligned(8)))  h2x2 { h2 a, b; };
struct __attribute__((packed, aligned(16))) h4 { h2 a, b, c, d; };

// ---------------------------------------------------------------------------
// Kernel 1 (pre, fused): thread = (n, cp, y, 4px), both channels of pair cp.
// Phase A: k,v dwconv3x3 from hr (unchanged from R7).
// Phase B: bilinear + q dwconv, REWRITTEN: no dynamic vector indexing (the
// old sel4 forced scratch spills). Bilinear becomes per-thread-constant
// sparse coefficient matrices (cw[6][5], rw[3][3], built once with
// constant-vs-register compares -> cndmask) applied to 3x5 unconditional
// register loads per channel. OOB rows/cols get zero weights (= ref zero-pad).
// grid 2048 x 256.
// ---------------------------------------------------------------------------
__global__ __launch_bounds__(256) void k_pre(
    const float* __restrict__ hr, const float* __restrict__ lr,
    const float* __restrict__ wq, const float* __restrict__ bq,
    const float* __restrict__ wk, const float* __restrict__ bk,
    const float* __restrict__ wv, const float* __restrict__ bv,
    h2* __restrict__ qpad, h2* __restrict__ kpad, h2* __restrict__ vpad,
    h2* __restrict__ lrup, h2* __restrict__ zgapA, h2* __restrict__ zgapB)
{
  const int t   = blockIdx.x * 256 + threadIdx.x;
  const int x4  = t & 31;
  const int y   = (t >> 5) & 127;
  const int ncp = t >> 12;             // n*CP+cp, uniform per block
  const int x   = x4 * 4;
  const int cp  = ncp & (CP - 1);
  const int n   = ncp >> 6;
  const int c0  = cp * 2;
  const h2 hz   = __floats2half2_rn(0.f, 0.f);

  // ---- phase A: k,v dwconv for both channels (unchanged) ----
  float ko[2][4], vo[2][4];
#pragma unroll
  for (int cc = 0; cc < 2; cc++) {
    const int c = c0 + cc;
    const float* hp = hr + (n * C + c) * HW;
    const float* wkc = wk + c * 9;     // uniform -> s_load
    const float* wvc = wv + c * 9;
    const float bkc = bk[c], bvc = bv[c];
#pragma unroll
    for (int j = 0; j < 4; j++) { ko[cc][j] = bkc; vo[cc][j] = bvc; }
#pragma unroll
    for (int r = 0; r < 3; r++) {
      const int gy = y + r - 1;
      const bool okr = (gy >= 0) && (gy < H);
      const int gyc = min(max(gy, 0), H - 1);
      const float* rp = hp + gyc * Wd;
      const f4u m = *(const f4u*)(rp + x);
      const float lft = rp[max(x - 1, 0)];
      const float rgt = rp[min(x + 4, Wd - 1)];
      float h[6];
      h[0] = (okr && x > 0) ? lft : 0.f;
      h[1] = okr ? m.x : 0.f;  h[2] = okr ? m.y : 0.f;
      h[3] = okr ? m.z : 0.f;  h[4] = okr ? m.w : 0.f;
      h[5] = (okr && x + 4 < Wd) ? rgt : 0.f;
#pragma unroll
      for (int dj = 0; dj < 3; dj++) {
        const float a = wkc[r * 3 + dj], b = wvc[r * 3 + dj];
#pragma unroll
        for (int j = 0; j < 4; j++) {
          ko[cc][j] += a * h[j + dj];
          vo[cc][j] += b * h[j + dj];
        }
      }
    }
  }

  h2* kr = kpad + ncp * KPLANE + (y + 2) * KRW + 2 + x;
  h2* vr = vpad + ncp * KPLANE + (y + 2) * KRW + 2 + x;
  {
    h2x2 k01; k01.a = __floats2half2_rn(ko[0][0], ko[1][0]);
              k01.b = __floats2half2_rn(ko[0][1], ko[1][1]);
    h2x2 k23; k23.a = __floats2half2_rn(ko[0][2], ko[1][2]);
              k23.b = __floats2half2_rn(ko[0][3], ko[1][3]);
    h2x2 v01; v01.a = __floats2half2_rn(vo[0][0], vo[1][0]);
              v01.b = __floats2half2_rn(vo[0][1], vo[1][1]);
    h2x2 v23; v23.a = __floats2half2_rn(vo[0][2], vo[1][2]);
              v23.b = __floats2half2_rn(vo[0][3], vo[1][3]);
    *(h2x2*)(kr) = k01; *(h2x2*)(kr + 2) = k23;
    *(h2x2*)(vr) = v01; *(h2x2*)(vr + 2) = v23;
  }

  // ---- phase B: bilinear coefficient matrices (once per thread) ----
  const float s = 63.0f / 127.0f;

  float rwm[3][3];            // rw[out_row r][loaded row t]
  int rA[3];                  // loaded-row byte... element offsets
  {
    int ry0[3]; float wyv[3]; bool okr[3];
#pragma unroll
    for (int r = 0; r < 3; r++) {
      const int gy = y + r - 1;
      okr[r] = (gy >= 0) && (gy < H);
      const int gyc = min(max(gy, 0), H - 1);
      const float fy = gyc * s;
      const int y0 = (int)fy;
      ry0[r] = y0;
      wyv[r] = fy - y0;
    }
    const int Y = ry0[0];     // nondecreasing; span <= 2
#pragma unroll
    for (int tt = 0; tt < 3; tt++) rA[tt] = min(Y + tt, LH - 1) * LW;
#pragma unroll
    for (int r = 0; r < 3; r++) {
      const int i0 = ry0[r] - Y;
      const int i1 = min(ry0[r] + 1, LH - 1) - Y;
#pragma unroll
      for (int tt = 0; tt < 3; tt++) {
        const float w = ((tt == i0) ? (1.f - wyv[r]) : 0.f)
                      + ((tt == i1) ? wyv[r] : 0.f);
        rwm[r][tt] = okr[r] ? w : 0.f;
      }
    }
  }

  float cwm[6][5];            // cw[out_col j][loaded col u]
  int XB;
  {
    int cx0[6]; float wxv[6]; bool okc[6];
#pragma unroll
    for (int j = 0; j < 6; j++) {
      const int gx = x + j - 1;
      okc[j] = (gx >= 0) && (gx < Wd);
      const int gxc = min(max(gx, 0), Wd - 1);
      const float fx = gxc * s;
      const int x0 = (int)fx;
      cx0[j] = x0;
      wxv[j] = fx - x0;
    }
    XB = min(cx0[0], LW - 5); // window [XB..XB+4]; i0<=4, i1<=4 (proven)
#pragma unroll
    for (int j = 0; j < 6; j++) {
      const int i0 = cx0[j] - XB;
      const int i1 = min(cx0[j] + 1, LW - 1) - XB;
#pragma unroll
      for (int u = 0; u < 5; u++) {
        const float w = ((u == i0) ? (1.f - wxv[j]) : 0.f)
                      + ((u == i1) ? wxv[j] : 0.f);
        cwm[j][u] = okc[j] ? w : 0.f;
      }
    }
  }

  // ---- phase B per channel: 6 loads + pure fma ----
  float qo[2][4], up[2][4];
#pragma unroll
  for (int cc = 0; cc < 2; cc++) {
    const int c = c0 + cc;
    const float* lp = lr + (n * C + c) * (LH * LW);
    const float* wqc = wq + c * 9;     // uniform -> s_load
    const float bqc = bq[c];
#pragma unroll
    for (int j = 0; j < 4; j++) qo[cc][j] = bqc;

    float R[3][5];
#pragma unroll
    for (int tt = 0; tt < 3; tt++) {
      const f4u m = *(const f4u*)(lp + rA[tt] + XB);
      R[tt][0] = m.x; R[tt][1] = m.y; R[tt][2] = m.z; R[tt][3] = m.w;
      R[tt][4] = lp[rA[tt] + XB + 4];
    }

    float yi[3][5];            // y-interpolated rows
#pragma unroll
    for (int r = 0; r < 3; r++)
#pragma unroll
      for (int u = 0; u < 5; u++)
        yi[r][u] = rwm[r][0] * R[0][u] + rwm[r][1] * R[1][u]
                 + rwm[r][2] * R[2][u];

#pragma unroll
    for (int r = 0; r < 3; r++) {
      float row[6];
#pragma unroll
      for (int j = 0; j < 6; j++)
        row[j] = cwm[j][0] * yi[r][0] + cwm[j][1] * yi[r][1]
               + cwm[j][2] * yi[r][2] + cwm[j][3] * yi[r][3]
               + cwm[j][4] * yi[r][4];
#pragma unroll
      for (int dj = 0; dj < 3; dj++) {
        const float a = wqc[r * 3 + dj];
#pragma unroll
        for (int j = 0; j < 4; j++) qo[cc][j] += a * row[j + dj];
      }
      if (r == 1) {
        up[cc][0] = row[1]; up[cc][1] = row[2];
        up[cc][2] = row[3]; up[cc][3] = row[4];
      }
    }
  }

  {
    h4 U;
    U.a = __floats2half2_rn(up[0][0], up[1][0]);
    U.b = __floats2half2_rn(up[0][1], up[1][1]);
    U.c = __floats2half2_rn(up[0][2], up[1][2]);
    U.d = __floats2half2_rn(up[0][3], up[1][3]);
    *(h4*)(lrup + ncp * HW + y * Wd + x) = U;   // 16B aligned
  }
  h2* qr = qpad + ncp * QPLANE + (y + 1) * QRW + 1 + x;
#pragma unroll
  for (int j = 0; j < 4; j++) qr[j] = __floats2half2_rn(qo[0][j], qo[1][j]);

  // ---- pad zeroing (ws is poisoned every call) ----
  if (x4 == 0) {
    kr[-2] = hz; kr[-1] = hz; vr[-2] = hz; vr[-1] = hz; qr[-1] = hz;
  }
  if (y == 0) {    // top pad rows
    h2* kz = kpad + ncp * KPLANE;
    h2* vz = vpad + ncp * KPLANE;
    h2* qz = qpad + ncp * QPLANE;
#pragma unroll
    for (int j = 0; j < 4; j++) {
      kz[2 + x + j] = hz;  kz[KRW + 2 + x + j] = hz;
      vz[2 + x + j] = hz;  vz[KRW + 2 + x + j] = hz;
      qz[1 + x + j] = hz;
    }
    if (x4 == 0) {
      kz[0] = hz; kz[1] = hz; kz[KRW] = hz; kz[KRW + 1] = hz;
      vz[0] = hz; vz[1] = hz; vz[KRW] = hz; vz[KRW + 1] = hz;
      qz[0] = hz;
    }
  }
  if (y == 127) {  // bottom pad rows
    h2* kz = kpad + ncp * KPLANE + 130 * KRW;
    h2* vz = vpad + ncp * KPLANE + 130 * KRW;
    h2* qz = qpad + ncp * QPLANE + 129 * QRW;
#pragma unroll
    for (int j = 0; j < 4; j++) {
      kz[2 + x + j] = hz;  kz[KRW + 2 + x + j] = hz;
      vz[2 + x + j] = hz;  vz[KRW + 2 + x + j] = hz;
      qz[1 + x + j] = hz;
    }
    if (x4 == 0) {
      kz[0] = hz; kz[1] = hz; kz[KRW] = hz; kz[KRW + 1] = hz;
      vz[0] = hz; vz[1] = hz; vz[KRW] = hz; vz[KRW + 1] = hz;
      qz[0] = hz;
    }
  }
  if (t < 256) zgapA[t] = hz;   // zero gap between qpad and lrup
  if (t < 4)   zgapB[t] = hz;   // tail gap after lrup
}

#define SIMT(idx, reg) { const float2 t_ = __half22float2(reg); \
  sim[idx] += qc.x * t_.x + qc.y * t_.y; }
#define VT(idx, reg) { const float2 t_ = __half22float2(reg); \
  acc0 += w[idx] * t_.x; acc1 += w[idx] * t_.y; }

// ---------------------------------------------------------------------------
// Kernel 2 (attention + gating fused) — UNCHANGED from R7 (proven).
// ---------------------------------------------------------------------------
__global__ __launch_bounds__(512) void k_attn(
    const h2* __restrict__ qpad, const h2* __restrict__ kpad,
    const h2* __restrict__ vpad, const h2* __restrict__ lrup,
    const float* __restrict__ wa, const float* __restrict__ ba,
    float* __restrict__ outb)
{
  __shared__ float red[25 * 512];   // 51.2 KB
  __shared__ float dsh[2 * 512];    // 4 KB

  const int tid = threadIdx.x;
  const int px = tid & 63;
  const int cgu = __builtin_amdgcn_readfirstlane(tid >> 6);  // wave-uniform
  const int x = blockIdx.x * 64 + px;
  const int y = blockIdx.y;
  const int n = blockIdx.z;
  const int cp0 = cgu * 8;

  float sim[25];
#pragma unroll
  for (int k = 0; k < 25; k++) sim[k] = 0.f;
  float d0a = 0.f, d1a = 0.f;

#pragma unroll 4
  for (int ci = 0; ci < 8; ci++) {
    const int cp = cp0 + ci;
    const h2* kp = kpad + (n * CP + cp) * KPLANE + y * KRW + x;
    const h2* qp = qpad + (n * CP + cp) * QPLANE + y * QRW + x;

    const f4h Q0 = *(const f4h*)(qp);            // dx -1..+2 (use a,b,c)
    const f4h Q1 = *(const f4h*)(qp + QRW);
    const f4h Q2 = *(const f4h*)(qp + 2 * QRW);
    const f4h A0 = *(const f4h*)(kp);            // dx -2..+1
    const f4h A1 = *(const f4h*)(kp + KRW);
    const f4h A2 = *(const f4h*)(kp + 2 * KRW);
    const f4h A3 = *(const f4h*)(kp + 3 * KRW);
    const f4h A4 = *(const f4h*)(kp + 4 * KRW);
    const h2 b0 = kp[4];                         // dx +2
    const h2 b1 = kp[KRW + 4];
    const h2 b2 = kp[2 * KRW + 4];
    const h2 b3 = kp[3 * KRW + 4];
    const h2 b4 = kp[4 * KRW + 4];

    const float2 qc = __half22float2(Q1.b);      // q center, both channels
    SIMT(0,  A0.a) SIMT(1,  A0.b) SIMT(2,  A0.c) SIMT(3,  A0.d) SIMT(4,  b0)
    SIMT(5,  A1.a) SIMT(6,  A1.b) SIMT(7,  A1.c) SIMT(8,  A1.d) SIMT(9,  b1)
    SIMT(10, A2.a) SIMT(11, A2.b) SIMT(12, A2.c) SIMT(13, A2.d) SIMT(14, b2)
    SIMT(15, A3.a) SIMT(16, A3.b) SIMT(17, A3.c) SIMT(18, A3.d) SIMT(19, b3)
    SIMT(20, A4.a) SIMT(21, A4.b) SIMT(22, A4.c) SIMT(23, A4.d) SIMT(24, b4)

    const float2 q3[9] = {
      __half22float2(Q0.a), __half22float2(Q0.b), __half22float2(Q0.c),
      __half22float2(Q1.a), __half22float2(Q1.b), __half22float2(Q1.c),
      __half22float2(Q2.a), __half22float2(Q2.b), __half22float2(Q2.c)};
    const float2 k3[9] = {
      __half22float2(A1.b), __half22float2(A1.c), __half22float2(A1.d),
      __half22float2(A2.b), __half22float2(A2.c), __half22float2(A2.d),
      __half22float2(A3.b), __half22float2(A3.c), __half22float2(A3.d)};
    const int c0 = 2 * cp;
    const float* w0q = wa + c0 * 9;              // [0..8]=ch c0, [9..17]=c0+1
    const float* w1q = wa + 2304 + c0 * 9;
    const float* w0k = wa + (C + c0) * 9;
    const float* w1k = wa + 2304 + (C + c0) * 9;
#pragma unroll
    for (int tp = 0; tp < 9; tp++) {
      d0a += w0q[tp] * q3[tp].x + w0q[9 + tp] * q3[tp].y
           + w0k[tp] * k3[tp].x + w0k[9 + tp] * k3[tp].y;
      d1a += w1q[tp] * q3[tp].x + w1q[9 + tp] * q3[tp].y
           + w1k[tp] * k3[tp].x + w1k[9 + tp] * k3[tp].y;
    }
  }

#pragma unroll
  for (int k = 0; k < 25; k++) red[k * 512 + tid] = sim[k];
  dsh[tid] = d0a;
  dsh[512 + tid] = d1a;
  __syncthreads();

  for (int k = cgu; k < 27; k += 8) {
    if (k < 25) {
      float s = 0.f;
#pragma unroll
      for (int g = 0; g < 8; g++) s += red[k * 512 + g * 64 + px];
      red[k * 512 + px] = s;
    } else if (k == 25) {
      float s = 0.f;
#pragma unroll
      for (int g = 0; g < 8; g++) s += dsh[g * 64 + px];
      dsh[px] = s;
    } else {
      float s = 0.f;
#pragma unroll
      for (int g = 0; g < 8; g++) s += dsh[512 + g * 64 + px];
      dsh[512 + px] = s;
    }
  }
  __syncthreads();

  float w[25];
  float m = -1e30f;
#pragma unroll
  for (int k = 0; k < 25; k++) { w[k] = red[k * 512 + px]; m = fmaxf(m, w[k]); }
  float tot = 0.f;
#pragma unroll
  for (int k = 0; k < 25; k++) { const float e = __expf(w[k] - m); w[k] = e; tot += e; }
  const float inv = __builtin_amdgcn_rcpf(tot);
#pragma unroll
  for (int k = 0; k < 25; k++) w[k] *= inv;
  const float g0 = __builtin_amdgcn_rcpf(1.f + __expf(-(dsh[px] + ba[0])));
  const float g1 = __builtin_amdgcn_rcpf(1.f + __expf(-(dsh[512 + px] + ba[1])));

#pragma unroll 4
  for (int ci = 0; ci < 8; ci++) {
    const int cp = cp0 + ci;
    const h2* vp = vpad + (n * CP + cp) * KPLANE + y * KRW + x;
    const f4h B0 = *(const f4h*)(vp);
    const f4h B1 = *(const f4h*)(vp + KRW);
    const f4h B2 = *(const f4h*)(vp + 2 * KRW);
    const f4h B3 = *(const f4h*)(vp + 3 * KRW);
    const f4h B4 = *(const f4h*)(vp + 4 * KRW);
    const h2 c0h = vp[4];
    const h2 c1h = vp[KRW + 4];
    const h2 c2h = vp[2 * KRW + 4];
    const h2 c3h = vp[3 * KRW + 4];
    const h2 c4h = vp[4 * KRW + 4];

    float acc0 = 0.f, acc1 = 0.f;
    VT(0,  B0.a) VT(1,  B0.b) VT(2,  B0.c) VT(3,  B0.d) VT(4,  c0h)
    VT(5,  B1.a) VT(6,  B1.b) VT(7,  B1.c) VT(8,  B1.d) VT(9,  c1h)
    VT(10, B2.a) VT(11, B2.b) VT(12, B2.c) VT(13, B2.d) VT(14, c2h)
    VT(15, B3.a) VT(16, B3.b) VT(17, B3.c) VT(18, B3.d) VT(19, c3h)
    VT(20, B4.a) VT(21, B4.b) VT(22, B4.c) VT(23, B4.d) VT(24, c4h)
    const float2 vc = __half22float2(B2.c);      // center tap
    const float2 lu = __half22float2(lrup[(n * CP + cp) * HW + y * Wd + x]);

    float* op = outb + (n * C + 2 * cp) * HW + y * Wd + x;
    op[0]  = lu.x + g0 * acc0 + g1 * vc.x;
    op[HW] = lu.y + g0 * acc1 + g1 * vc.y;
  }
}

// ---------------------------------------------------------------------------
extern "C" void kernel_launch(void* const* d_in, const int* in_sizes, int n_in,
                              void* d_out, int out_size, void* d_ws,
                              size_t ws_size, hipStream_t stream)
{
  const float* hr = (const float*)d_in[0];
  const float* lr = (const float*)d_in[1];
  const float* wq = (const float*)d_in[2];
  const float* bq = (const float*)d_in[3];
  const float* wk = (const float*)d_in[4];
  const float* bk = (const float*)d_in[5];
  const float* wv = (const float*)d_in[6];
  const float* bv = (const float*)d_in[7];
  const float* wa = (const float*)d_in[8];
  const float* ba = (const float*)d_in[9];

  float* out = (float*)d_out;
  h2* ws2 = (h2*)d_ws;

  // layout (half2 elems): kpad | vpad | qpad | zgapA(256) | lrup | zgapB(4)
  h2* kpad  = ws2;
  h2* vpad  = kpad + KSZ;
  h2* qpad  = vpad + KSZ;
  h2* zgapA = qpad + QSZ;
  h2* lrupb = zgapA + 256;
  h2* zgapB = lrupb + LSZ;

  k_pre<<<dim3(2048), dim3(256), 0, stream>>>(
      hr, lr, wq, bq, wk, bk, wv, bv, qpad, kpad, vpad, lrupb, zgapA, zgapB);
  k_attn<<<dim3(2, 128, 2), dim3(512), 0, stream>>>(
      qpad, kpad, vpad, lrupb, wa, ba, out);
}

// Round 9
// 126.699 us; speedup vs baseline: 1.6628x; 1.0958x over previous
//
#include <hip/hip_runtime.h>
#include <hip/hip_fp16.h>
#include <math.h>

constexpr int C  = 128;
constexpr int H  = 128;
constexpr int Wd = 128;
constexpr int HW = H * Wd;
constexpr int LH = 64, LW = 64;
constexpr int CP = 64;                  // channel PAIRS per image (half2-packed)

constexpr int KRW = 130;                // k/v row stride (h2 elems), 2 left pads
constexpr int KPLANE = 132 * KRW;       // 2 top + 128 + 2 bottom rows = 17160
constexpr int QRW = 129;                // q row stride, 1 left pad
constexpr int QPLANE = 130 * QRW;       // 1 top + 128 + 1 bottom rows = 16770
constexpr int KSZ = 2 * CP * KPLANE;    // 2,196,480 h2
constexpr int QSZ = 2 * CP * QPLANE;    // 2,146,560 h2
constexpr int LSZ = 2 * CP * HW;        // 2,097,152 h2
constexpr int WAHSZ = 2304;             // packed gating weights (h2)
// ws: 2*KSZ + QSZ + 256 + LSZ + 4 + 2304 ~ 34.6 MB (ws is 256 MiB per R8 fills)

typedef _Float16 __attribute__((ext_vector_type(2))) v2h;

#if __has_builtin(__builtin_amdgcn_fdot2)
#define DOT2(a, b, c) __builtin_amdgcn_fdot2((a), (b), (c), false)
#else
#define DOT2(a, b, c) ((c) + (float)(a).x * (float)(b).x + (float)(a).y * (float)(b).y)
#endif

struct __attribute__((packed, aligned(4)))  f4u { float x, y, z, w; };
struct __attribute__((packed, aligned(4)))  f4p { v2h a, b, c, d; };
struct __attribute__((packed, aligned(8)))  h2x2 { v2h a, b; };
struct __attribute__((packed, aligned(16))) h4 { v2h a, b, c, d; };

__device__ __forceinline__ v2h pack2(float a, float b) {
  v2h r; r.x = (_Float16)a; r.y = (_Float16)b; return r;
}

// ---------------------------------------------------------------------------
// Kernel 1 (pre, fused): thread = (n, cp, y, 4px), both channels of pair cp.
// Phase A: k,v dwconv3x3 from hr. Phase B: bilinear via per-thread sparse
// coefficient matrices (R8, scratch-free) + q dwconv. Outputs half2-packed
// padded planes. NEW: threads t<2304 also pack the gating-conv weights into
// a half2 table wah[cp][o][src][tap] for k_attn's fdot2 path.
// grid 2048 x 256.
// ---------------------------------------------------------------------------
__global__ __launch_bounds__(256) void k_pre(
    const float* __restrict__ hr, const float* __restrict__ lr,
    const float* __restrict__ wq, const float* __restrict__ bq,
    const float* __restrict__ wk, const float* __restrict__ bk,
    const float* __restrict__ wv, const float* __restrict__ bv,
    const float* __restrict__ wa,
    v2h* __restrict__ qpad, v2h* __restrict__ kpad, v2h* __restrict__ vpad,
    v2h* __restrict__ lrup, v2h* __restrict__ zgapA, v2h* __restrict__ zgapB,
    v2h* __restrict__ wah)
{
  const int t   = blockIdx.x * 256 + threadIdx.x;
  const int x4  = t & 31;
  const int y   = (t >> 5) & 127;
  const int ncp = t >> 12;             // n*CP+cp, uniform per block
  const int x   = x4 * 4;
  const int cp  = ncp & (CP - 1);
  const int n   = ncp >> 6;
  const int c0  = cp * 2;
  const v2h hz  = pack2(0.f, 0.f);

  // ---- gating-weight packing (independent side job) ----
  if (t < WAHSZ) {
    const int cpw = t / 36, r = t - cpw * 36;
    const int o = r / 18, s2 = (r - o * 18) / 9, tap = r - o * 18 - s2 * 9;
    const int c = s2 * 128 + 2 * cpw;
    wah[t] = pack2(wa[(o * 256 + c) * 9 + tap], wa[(o * 256 + c + 1) * 9 + tap]);
  }

  // ---- phase A: k,v dwconv for both channels ----
  float ko[2][4], vo[2][4];
#pragma unroll
  for (int cc = 0; cc < 2; cc++) {
    const int c = c0 + cc;
    const float* hp = hr + (n * C + c) * HW;
    const float* wkc = wk + c * 9;     // uniform -> s_load
    const float* wvc = wv + c * 9;
    const float bkc = bk[c], bvc = bv[c];
#pragma unroll
    for (int j = 0; j < 4; j++) { ko[cc][j] = bkc; vo[cc][j] = bvc; }
#pragma unroll
    for (int r = 0; r < 3; r++) {
      const int gy = y + r - 1;
      const bool okr = (gy >= 0) && (gy < H);
      const int gyc = min(max(gy, 0), H - 1);
      const float* rp = hp + gyc * Wd;
      const f4u m = *(const f4u*)(rp + x);
      const float lft = rp[max(x - 1, 0)];
      const float rgt = rp[min(x + 4, Wd - 1)];
      float h[6];
      h[0] = (okr && x > 0) ? lft : 0.f;
      h[1] = okr ? m.x : 0.f;  h[2] = okr ? m.y : 0.f;
      h[3] = okr ? m.z : 0.f;  h[4] = okr ? m.w : 0.f;
      h[5] = (okr && x + 4 < Wd) ? rgt : 0.f;
#pragma unroll
      for (int dj = 0; dj < 3; dj++) {
        const float a = wkc[r * 3 + dj], b = wvc[r * 3 + dj];
#pragma unroll
        for (int j = 0; j < 4; j++) {
          ko[cc][j] += a * h[j + dj];
          vo[cc][j] += b * h[j + dj];
        }
      }
    }
  }

  v2h* kr = kpad + ncp * KPLANE + (y + 2) * KRW + 2 + x;
  v2h* vr = vpad + ncp * KPLANE + (y + 2) * KRW + 2 + x;
  {
    h2x2 k01; k01.a = pack2(ko[0][0], ko[1][0]); k01.b = pack2(ko[0][1], ko[1][1]);
    h2x2 k23; k23.a = pack2(ko[0][2], ko[1][2]); k23.b = pack2(ko[0][3], ko[1][3]);
    h2x2 v01; v01.a = pack2(vo[0][0], vo[1][0]); v01.b = pack2(vo[0][1], vo[1][1]);
    h2x2 v23; v23.a = pack2(vo[0][2], vo[1][2]); v23.b = pack2(vo[0][3], vo[1][3]);
    *(h2x2*)(kr) = k01; *(h2x2*)(kr + 2) = k23;
    *(h2x2*)(vr) = v01; *(h2x2*)(vr + 2) = v23;
  }

  // ---- phase B: bilinear coefficient matrices (once per thread) ----
  const float s = 63.0f / 127.0f;

  float rwm[3][3]; int rA[3];
  {
    int ry0[3]; float wyv[3]; bool okr[3];
#pragma unroll
    for (int r = 0; r < 3; r++) {
      const int gy = y + r - 1;
      okr[r] = (gy >= 0) && (gy < H);
      const int gyc = min(max(gy, 0), H - 1);
      const float fy = gyc * s;
      const int y0 = (int)fy;
      ry0[r] = y0;
      wyv[r] = fy - y0;
    }
    const int Y = ry0[0];
#pragma unroll
    for (int tt = 0; tt < 3; tt++) rA[tt] = min(Y + tt, LH - 1) * LW;
#pragma unroll
    for (int r = 0; r < 3; r++) {
      const int i0 = ry0[r] - Y;
      const int i1 = min(ry0[r] + 1, LH - 1) - Y;
#pragma unroll
      for (int tt = 0; tt < 3; tt++) {
        const float w = ((tt == i0) ? (1.f - wyv[r]) : 0.f)
                      + ((tt == i1) ? wyv[r] : 0.f);
        rwm[r][tt] = okr[r] ? w : 0.f;
      }
    }
  }

  float cwm[6][5]; int XB;
  {
    int cx0[6]; float wxv[6]; bool okc[6];
#pragma unroll
    for (int j = 0; j < 6; j++) {
      const int gx = x + j - 1;
      okc[j] = (gx >= 0) && (gx < Wd);
      const int gxc = min(max(gx, 0), Wd - 1);
      const float fx = gxc * s;
      const int x0 = (int)fx;
      cx0[j] = x0;
      wxv[j] = fx - x0;
    }
    XB = min(cx0[0], LW - 5);
#pragma unroll
    for (int j = 0; j < 6; j++) {
      const int i0 = cx0[j] - XB;
      const int i1 = min(cx0[j] + 1, LW - 1) - XB;
#pragma unroll
      for (int u = 0; u < 5; u++) {
        const float w = ((u == i0) ? (1.f - wxv[j]) : 0.f)
                      + ((u == i1) ? wxv[j] : 0.f);
        cwm[j][u] = okc[j] ? w : 0.f;
      }
    }
  }

  float qo[2][4], up[2][4];
#pragma unroll
  for (int cc = 0; cc < 2; cc++) {
    const int c = c0 + cc;
    const float* lp = lr + (n * C + c) * (LH * LW);
    const float* wqc = wq + c * 9;
    const float bqc = bq[c];
#pragma unroll
    for (int j = 0; j < 4; j++) qo[cc][j] = bqc;

    float R[3][5];
#pragma unroll
    for (int tt = 0; tt < 3; tt++) {
      const f4u m = *(const f4u*)(lp + rA[tt] + XB);
      R[tt][0] = m.x; R[tt][1] = m.y; R[tt][2] = m.z; R[tt][3] = m.w;
      R[tt][4] = lp[rA[tt] + XB + 4];
    }

    float yi[3][5];
#pragma unroll
    for (int r = 0; r < 3; r++)
#pragma unroll
      for (int u = 0; u < 5; u++)
        yi[r][u] = rwm[r][0] * R[0][u] + rwm[r][1] * R[1][u]
                 + rwm[r][2] * R[2][u];

#pragma unroll
    for (int r = 0; r < 3; r++) {
      float row[6];
#pragma unroll
      for (int j = 0; j < 6; j++)
        row[j] = cwm[j][0] * yi[r][0] + cwm[j][1] * yi[r][1]
               + cwm[j][2] * yi[r][2] + cwm[j][3] * yi[r][3]
               + cwm[j][4] * yi[r][4];
#pragma unroll
      for (int dj = 0; dj < 3; dj++) {
        const float a = wqc[r * 3 + dj];
#pragma unroll
        for (int j = 0; j < 4; j++) qo[cc][j] += a * row[j + dj];
      }
      if (r == 1) {
        up[cc][0] = row[1]; up[cc][1] = row[2];
        up[cc][2] = row[3]; up[cc][3] = row[4];
      }
    }
  }

  {
    h4 U;
    U.a = pack2(up[0][0], up[1][0]); U.b = pack2(up[0][1], up[1][1]);
    U.c = pack2(up[0][2], up[1][2]); U.d = pack2(up[0][3], up[1][3]);
    *(h4*)(lrup + ncp * HW + y * Wd + x) = U;
  }
  v2h* qr = qpad + ncp * QPLANE + (y + 1) * QRW + 1 + x;
#pragma unroll
  for (int j = 0; j < 4; j++) qr[j] = pack2(qo[0][j], qo[1][j]);

  // ---- pad zeroing (ws is poisoned every call) ----
  if (x4 == 0) {
    kr[-2] = hz; kr[-1] = hz; vr[-2] = hz; vr[-1] = hz; qr[-1] = hz;
  }
  if (y == 0) {
    v2h* kz = kpad + ncp * KPLANE;
    v2h* vz = vpad + ncp * KPLANE;
    v2h* qz = qpad + ncp * QPLANE;
#pragma unroll
    for (int j = 0; j < 4; j++) {
      kz[2 + x + j] = hz;  kz[KRW + 2 + x + j] = hz;
      vz[2 + x + j] = hz;  vz[KRW + 2 + x + j] = hz;
      qz[1 + x + j] = hz;
    }
    if (x4 == 0) {
      kz[0] = hz; kz[1] = hz; kz[KRW] = hz; kz[KRW + 1] = hz;
      vz[0] = hz; vz[1] = hz; vz[KRW] = hz; vz[KRW + 1] = hz;
      qz[0] = hz;
    }
  }
  if (y == 127) {
    v2h* kz = kpad + ncp * KPLANE + 130 * KRW;
    v2h* vz = vpad + ncp * KPLANE + 130 * KRW;
    v2h* qz = qpad + ncp * QPLANE + 129 * QRW;
#pragma unroll
    for (int j = 0; j < 4; j++) {
      kz[2 + x + j] = hz;  kz[KRW + 2 + x + j] = hz;
      vz[2 + x + j] = hz;  vz[KRW + 2 + x + j] = hz;
      qz[1 + x + j] = hz;
    }
    if (x4 == 0) {
      kz[0] = hz; kz[1] = hz; kz[KRW] = hz; kz[KRW + 1] = hz;
      vz[0] = hz; vz[1] = hz; vz[KRW] = hz; vz[KRW + 1] = hz;
      qz[0] = hz;
    }
  }
  if (t < 256) zgapA[t] = hz;
  if (t < 4)   zgapB[t] = hz;
}

// ---------------------------------------------------------------------------
// Kernel 2 (attention + gating fused): dot2 edition.
// sim & gating: v_dot2_f32_f16 (fp16 pair mul, fp32 acc — same numerics as
// before, 1 instr instead of 2 cvt + 2 fma). Gating weights from packed
// half2 table (wave-uniform -> s_load batches). Value pass: v_pk_fma_f16
// with two split accumulators (fp16 over 25 taps only), fp32 combine.
// LDS reduce + softmax unchanged (fp32). grid (2,128,2) x 512.
// ---------------------------------------------------------------------------
__global__ __launch_bounds__(512) void k_attn(
    const v2h* __restrict__ qpad, const v2h* __restrict__ kpad,
    const v2h* __restrict__ vpad, const v2h* __restrict__ lrup,
    const v2h* __restrict__ wah, const float* __restrict__ ba,
    float* __restrict__ outb)
{
  __shared__ float red[25 * 512];   // 51.2 KB
  __shared__ float dsh[2 * 512];    // 4 KB

  const int tid = threadIdx.x;
  const int px = tid & 63;
  const int cgu = __builtin_amdgcn_readfirstlane(tid >> 6);  // wave-uniform
  const int x = blockIdx.x * 64 + px;
  const int y = blockIdx.y;
  const int n = blockIdx.z;
  const int cp0 = cgu * 8;

  float sim[25];
#pragma unroll
  for (int k = 0; k < 25; k++) sim[k] = 0.f;
  float d0a = 0.f, d1a = 0.f;

#pragma unroll 4
  for (int ci = 0; ci < 8; ci++) {
    const int cp = cp0 + ci;
    const v2h* kp = kpad + (n * CP + cp) * KPLANE + y * KRW + x;
    const v2h* qp = qpad + (n * CP + cp) * QPLANE + y * QRW + x;
    const v2h* wp = wah + cp * 36;               // uniform -> s_load

    const f4p Q0 = *(const f4p*)(qp);            // dx -1..+2 (use a,b,c)
    const f4p Q1 = *(const f4p*)(qp + QRW);
    const f4p Q2 = *(const f4p*)(qp + 2 * QRW);
    const f4p A0 = *(const f4p*)(kp);            // dx -2..+1
    const f4p A1 = *(const f4p*)(kp + KRW);
    const f4p A2 = *(const f4p*)(kp + 2 * KRW);
    const f4p A3 = *(const f4p*)(kp + 3 * KRW);
    const f4p A4 = *(const f4p*)(kp + 4 * KRW);
    const v2h b0 = kp[4];                        // dx +2
    const v2h b1 = kp[KRW + 4];
    const v2h b2 = kp[2 * KRW + 4];
    const v2h b3 = kp[3 * KRW + 4];
    const v2h b4 = kp[4 * KRW + 4];

    const v2h qc = Q1.b;                         // q center (both channels)
    sim[0]  = DOT2(qc, A0.a, sim[0]);  sim[1]  = DOT2(qc, A0.b, sim[1]);
    sim[2]  = DOT2(qc, A0.c, sim[2]);  sim[3]  = DOT2(qc, A0.d, sim[3]);
    sim[4]  = DOT2(qc, b0,   sim[4]);
    sim[5]  = DOT2(qc, A1.a, sim[5]);  sim[6]  = DOT2(qc, A1.b, sim[6]);
    sim[7]  = DOT2(qc, A1.c, sim[7]);  sim[8]  = DOT2(qc, A1.d, sim[8]);
    sim[9]  = DOT2(qc, b1,   sim[9]);
    sim[10] = DOT2(qc, A2.a, sim[10]); sim[11] = DOT2(qc, A2.b, sim[11]);
    sim[12] = DOT2(qc, A2.c, sim[12]); sim[13] = DOT2(qc, A2.d, sim[13]);
    sim[14] = DOT2(qc, b2,   sim[14]);
    sim[15] = DOT2(qc, A3.a, sim[15]); sim[16] = DOT2(qc, A3.b, sim[16]);
    sim[17] = DOT2(qc, A3.c, sim[17]); sim[18] = DOT2(qc, A3.d, sim[18]);
    sim[19] = DOT2(qc, b3,   sim[19]);
    sim[20] = DOT2(qc, A4.a, sim[20]); sim[21] = DOT2(qc, A4.b, sim[21]);
    sim[22] = DOT2(qc, A4.c, sim[22]); sim[23] = DOT2(qc, A4.d, sim[23]);
    sim[24] = DOT2(qc, b4,   sim[24]);

    // gating: 9 q-taps and 9 k-taps per output, packed fp16 weights
    const v2h q3[9] = {Q0.a, Q0.b, Q0.c, Q1.a, Q1.b, Q1.c, Q2.a, Q2.b, Q2.c};
    const v2h k3[9] = {A1.b, A1.c, A1.d, A2.b, A2.c, A2.d, A3.b, A3.c, A3.d};
#pragma unroll
    for (int tp = 0; tp < 9; tp++) {
      d0a = DOT2(wp[tp],      q3[tp], d0a);
      d0a = DOT2(wp[9 + tp],  k3[tp], d0a);
      d1a = DOT2(wp[18 + tp], q3[tp], d1a);
      d1a = DOT2(wp[27 + tp], k3[tp], d1a);
    }
  }

#pragma unroll
  for (int k = 0; k < 25; k++) red[k * 512 + tid] = sim[k];
  dsh[tid] = d0a;
  dsh[512 + tid] = d1a;
  __syncthreads();

  for (int k = cgu; k < 27; k += 8) {
    if (k < 25) {
      float s = 0.f;
#pragma unroll
      for (int g = 0; g < 8; g++) s += red[k * 512 + g * 64 + px];
      red[k * 512 + px] = s;
    } else if (k == 25) {
      float s = 0.f;
#pragma unroll
      for (int g = 0; g < 8; g++) s += dsh[g * 64 + px];
      dsh[px] = s;
    } else {
      float s = 0.f;
#pragma unroll
      for (int g = 0; g < 8; g++) s += dsh[512 + g * 64 + px];
      dsh[512 + px] = s;
    }
  }
  __syncthreads();

  float w[25];
  float m = -1e30f;
#pragma unroll
  for (int k = 0; k < 25; k++) { w[k] = red[k * 512 + px]; m = fmaxf(m, w[k]); }
  float tot = 0.f;
#pragma unroll
  for (int k = 0; k < 25; k++) { const float e = __expf(w[k] - m); w[k] = e; tot += e; }
  const float inv = __builtin_amdgcn_rcpf(tot);
  v2h wpk[25];
#pragma unroll
  for (int k = 0; k < 25; k++) {
    const float wf = w[k] * inv;
    wpk[k] = pack2(wf, wf);
  }
  const float g0 = __builtin_amdgcn_rcpf(1.f + __expf(-(dsh[px] + ba[0])));
  const float g1 = __builtin_amdgcn_rcpf(1.f + __expf(-(dsh[512 + px] + ba[1])));

  // value pass + epilogue (pk_fma, two split fp16 accumulators)
#pragma unroll 4
  for (int ci = 0; ci < 8; ci++) {
    const int cp = cp0 + ci;
    const v2h* vp = vpad + (n * CP + cp) * KPLANE + y * KRW + x;
    const f4p B0 = *(const f4p*)(vp);
    const f4p B1 = *(const f4p*)(vp + KRW);
    const f4p B2 = *(const f4p*)(vp + 2 * KRW);
    const f4p B3 = *(const f4p*)(vp + 3 * KRW);
    const f4p B4 = *(const f4p*)(vp + 4 * KRW);
    const v2h c0h = vp[4];
    const v2h c1h = vp[KRW + 4];
    const v2h c2h = vp[2 * KRW + 4];
    const v2h c3h = vp[3 * KRW + 4];
    const v2h c4h = vp[4 * KRW + 4];

    v2h accA = wpk[0] * B0.a;            // rows 0,2,4
    accA += wpk[1]  * B0.b;  accA += wpk[2]  * B0.c;
    accA += wpk[3]  * B0.d;  accA += wpk[4]  * c0h;
    v2h accB = wpk[5] * B1.a;            // rows 1,3
    accB += wpk[6]  * B1.b;  accB += wpk[7]  * B1.c;
    accB += wpk[8]  * B1.d;  accB += wpk[9]  * c1h;
    accA += wpk[10] * B2.a;  accA += wpk[11] * B2.b;
    accA += wpk[12] * B2.c;  accA += wpk[13] * B2.d;
    accA += wpk[14] * c2h;
    accB += wpk[15] * B3.a;  accB += wpk[16] * B3.b;
    accB += wpk[17] * B3.c;  accB += wpk[18] * B3.d;
    accB += wpk[19] * c3h;
    accA += wpk[20] * B4.a;  accA += wpk[21] * B4.b;
    accA += wpk[22] * B4.c;  accA += wpk[23] * B4.d;
    accA += wpk[24] * c4h;

    const float acc0 = (float)accA.x + (float)accB.x;
    const float acc1 = (float)accA.y + (float)accB.y;
    const v2h vc = B2.c;                 // center tap
    const v2h lu = lrup[(n * CP + cp) * HW + y * Wd + x];

    float* op = outb + (n * C + 2 * cp) * HW + y * Wd + x;
    op[0]  = (float)lu.x + g0 * acc0 + g1 * (float)vc.x;
    op[HW] = (float)lu.y + g0 * acc1 + g1 * (float)vc.y;
  }
}

// ---------------------------------------------------------------------------
extern "C" void kernel_launch(void* const* d_in, const int* in_sizes, int n_in,
                              void* d_out, int out_size, void* d_ws,
                              size_t ws_size, hipStream_t stream)
{
  const float* hr = (const float*)d_in[0];
  const float* lr = (const float*)d_in[1];
  const float* wq = (const float*)d_in[2];
  const float* bq = (const float*)d_in[3];
  const float* wk = (const float*)d_in[4];
  const float* bk = (const float*)d_in[5];
  const float* wv = (const float*)d_in[6];
  const float* bv = (const float*)d_in[7];
  const float* wa = (const float*)d_in[8];
  const float* ba = (const float*)d_in[9];

  float* out = (float*)d_out;
  v2h* ws2 = (v2h*)d_ws;

  // layout (h2 elems): kpad | vpad | qpad | zgapA(256) | lrup | zgapB(4) | wah
  v2h* kpad  = ws2;
  v2h* vpad  = kpad + KSZ;
  v2h* qpad  = vpad + KSZ;
  v2h* zgapA = qpad + QSZ;
  v2h* lrupb = zgapA + 256;
  v2h* zgapB = lrupb + LSZ;
  v2h* wahb  = zgapB + 4;

  k_pre<<<dim3(2048), dim3(256), 0, stream>>>(
      hr, lr, wq, bq, wk, bk, wv, bv, wa,
      qpad, kpad, vpad, lrupb, zgapA, zgapB, wahb);
  k_attn<<<dim3(2, 128, 2), dim3(512), 0, stream>>>(
      qpad, kpad, vpad, lrupb, wahb, ba, out);
}

// Round 10
// 125.489 us; speedup vs baseline: 1.6788x; 1.0096x over previous
//
#include <hip/hip_runtime.h>
#include <hip/hip_fp16.h>
#include <math.h>

constexpr int C  = 128;
constexpr int H  = 128;
constexpr int Wd = 128;
constexpr int HW = H * Wd;
constexpr int LH = 64, LW = 64;
constexpr int CP = 64;                  // channel PAIRS per image (half2-packed)

constexpr int KRW = 130;                // k/v row stride (h2 elems), 2 left pads
constexpr int KPLANE = 132 * KRW;       // 2 top + 128 + 2 bottom rows = 17160
constexpr int QRW = 129;                // q row stride, 1 left pad
constexpr int QPLANE = 130 * QRW;       // 1 top + 128 + 1 bottom rows = 16770
constexpr int KSZ = 2 * CP * KPLANE;    // h2 elems
constexpr int QSZ = 2 * CP * QPLANE;
constexpr int LSZ = 2 * CP * HW;
constexpr int WAHSZ = 2304;             // packed gating weights (h2)

typedef _Float16 __attribute__((ext_vector_type(2))) v2h;

#if __has_builtin(__builtin_amdgcn_fdot2)
#define DOT2(a, b, c) __builtin_amdgcn_fdot2((a), (b), (c), false)
#else
#define DOT2(a, b, c) ((c) + (float)(a).x * (float)(b).x + (float)(a).y * (float)(b).y)
#endif

struct __attribute__((packed, aligned(4)))  f4u { float x, y, z, w; };
struct __attribute__((packed, aligned(4)))  f4p { v2h a, b, c, d; };
struct __attribute__((packed, aligned(8)))  h2x2 { v2h a, b; };
struct __attribute__((packed, aligned(16))) h4 { v2h a, b, c, d; };

__device__ __forceinline__ v2h pack2(float a, float b) {
  v2h r; r.x = (_Float16)a; r.y = (_Float16)b; return r;
}

// ---------------------------------------------------------------------------
// Kernel 1 (pre) — UNCHANGED from R9 (proven: scratch-free bilinear via
// sparse coefficient matrices, fused k/v/q dwconv, half2-packed padded
// planes, gating-weight half2 packing side job).
// ---------------------------------------------------------------------------
__global__ __launch_bounds__(256) void k_pre(
    const float* __restrict__ hr, const float* __restrict__ lr,
    const float* __restrict__ wq, const float* __restrict__ bq,
    const float* __restrict__ wk, const float* __restrict__ bk,
    const float* __restrict__ wv, const float* __restrict__ bv,
    const float* __restrict__ wa,
    v2h* __restrict__ qpad, v2h* __restrict__ kpad, v2h* __restrict__ vpad,
    v2h* __restrict__ lrup, v2h* __restrict__ zgapA, v2h* __restrict__ zgapB,
    v2h* __restrict__ wah)
{
  const int t   = blockIdx.x * 256 + threadIdx.x;
  const int x4  = t & 31;
  const int y   = (t >> 5) & 127;
  const int ncp = t >> 12;
  const int x   = x4 * 4;
  const int cp  = ncp & (CP - 1);
  const int n   = ncp >> 6;
  const int c0  = cp * 2;
  const v2h hz  = pack2(0.f, 0.f);

  if (t < WAHSZ) {
    const int cpw = t / 36, r = t - cpw * 36;
    const int o = r / 18, s2 = (r - o * 18) / 9, tap = r - o * 18 - s2 * 9;
    const int c = s2 * 128 + 2 * cpw;
    wah[t] = pack2(wa[(o * 256 + c) * 9 + tap], wa[(o * 256 + c + 1) * 9 + tap]);
  }

  float ko[2][4], vo[2][4];
#pragma unroll
  for (int cc = 0; cc < 2; cc++) {
    const int c = c0 + cc;
    const float* hp = hr + (n * C + c) * HW;
    const float* wkc = wk + c * 9;
    const float* wvc = wv + c * 9;
    const float bkc = bk[c], bvc = bv[c];
#pragma unroll
    for (int j = 0; j < 4; j++) { ko[cc][j] = bkc; vo[cc][j] = bvc; }
#pragma unroll
    for (int r = 0; r < 3; r++) {
      const int gy = y + r - 1;
      const bool okr = (gy >= 0) && (gy < H);
      const int gyc = min(max(gy, 0), H - 1);
      const float* rp = hp + gyc * Wd;
      const f4u m = *(const f4u*)(rp + x);
      const float lft = rp[max(x - 1, 0)];
      const float rgt = rp[min(x + 4, Wd - 1)];
      float h[6];
      h[0] = (okr && x > 0) ? lft : 0.f;
      h[1] = okr ? m.x : 0.f;  h[2] = okr ? m.y : 0.f;
      h[3] = okr ? m.z : 0.f;  h[4] = okr ? m.w : 0.f;
      h[5] = (okr && x + 4 < Wd) ? rgt : 0.f;
#pragma unroll
      for (int dj = 0; dj < 3; dj++) {
        const float a = wkc[r * 3 + dj], b = wvc[r * 3 + dj];
#pragma unroll
        for (int j = 0; j < 4; j++) {
          ko[cc][j] += a * h[j + dj];
          vo[cc][j] += b * h[j + dj];
        }
      }
    }
  }

  v2h* kr = kpad + ncp * KPLANE + (y + 2) * KRW + 2 + x;
  v2h* vr = vpad + ncp * KPLANE + (y + 2) * KRW + 2 + x;
  {
    h2x2 k01; k01.a = pack2(ko[0][0], ko[1][0]); k01.b = pack2(ko[0][1], ko[1][1]);
    h2x2 k23; k23.a = pack2(ko[0][2], ko[1][2]); k23.b = pack2(ko[0][3], ko[1][3]);
    h2x2 v01; v01.a = pack2(vo[0][0], vo[1][0]); v01.b = pack2(vo[0][1], vo[1][1]);
    h2x2 v23; v23.a = pack2(vo[0][2], vo[1][2]); v23.b = pack2(vo[0][3], vo[1][3]);
    *(h2x2*)(kr) = k01; *(h2x2*)(kr + 2) = k23;
    *(h2x2*)(vr) = v01; *(h2x2*)(vr + 2) = v23;
  }

  const float s = 63.0f / 127.0f;

  float rwm[3][3]; int rA[3];
  {
    int ry0[3]; float wyv[3]; bool okr[3];
#pragma unroll
    for (int r = 0; r < 3; r++) {
      const int gy = y + r - 1;
      okr[r] = (gy >= 0) && (gy < H);
      const int gyc = min(max(gy, 0), H - 1);
      const float fy = gyc * s;
      const int y0 = (int)fy;
      ry0[r] = y0;
      wyv[r] = fy - y0;
    }
    const int Y = ry0[0];
#pragma unroll
    for (int tt = 0; tt < 3; tt++) rA[tt] = min(Y + tt, LH - 1) * LW;
#pragma unroll
    for (int r = 0; r < 3; r++) {
      const int i0 = ry0[r] - Y;
      const int i1 = min(ry0[r] + 1, LH - 1) - Y;
#pragma unroll
      for (int tt = 0; tt < 3; tt++) {
        const float w = ((tt == i0) ? (1.f - wyv[r]) : 0.f)
                      + ((tt == i1) ? wyv[r] : 0.f);
        rwm[r][tt] = okr[r] ? w : 0.f;
      }
    }
  }

  float cwm[6][5]; int XB;
  {
    int cx0[6]; float wxv[6]; bool okc[6];
#pragma unroll
    for (int j = 0; j < 6; j++) {
      const int gx = x + j - 1;
      okc[j] = (gx >= 0) && (gx < Wd);
      const int gxc = min(max(gx, 0), Wd - 1);
      const float fx = gxc * s;
      const int x0 = (int)fx;
      cx0[j] = x0;
      wxv[j] = fx - x0;
    }
    XB = min(cx0[0], LW - 5);
#pragma unroll
    for (int j = 0; j < 6; j++) {
      const int i0 = cx0[j] - XB;
      const int i1 = min(cx0[j] + 1, LW - 1) - XB;
#pragma unroll
      for (int u = 0; u < 5; u++) {
        const float w = ((u == i0) ? (1.f - wxv[j]) : 0.f)
                      + ((u == i1) ? wxv[j] : 0.f);
        cwm[j][u] = okc[j] ? w : 0.f;
      }
    }
  }

  float qo[2][4], up[2][4];
#pragma unroll
  for (int cc = 0; cc < 2; cc++) {
    const int c = c0 + cc;
    const float* lp = lr + (n * C + c) * (LH * LW);
    const float* wqc = wq + c * 9;
    const float bqc = bq[c];
#pragma unroll
    for (int j = 0; j < 4; j++) qo[cc][j] = bqc;

    float R[3][5];
#pragma unroll
    for (int tt = 0; tt < 3; tt++) {
      const f4u m = *(const f4u*)(lp + rA[tt] + XB);
      R[tt][0] = m.x; R[tt][1] = m.y; R[tt][2] = m.z; R[tt][3] = m.w;
      R[tt][4] = lp[rA[tt] + XB + 4];
    }

    float yi[3][5];
#pragma unroll
    for (int r = 0; r < 3; r++)
#pragma unroll
      for (int u = 0; u < 5; u++)
        yi[r][u] = rwm[r][0] * R[0][u] + rwm[r][1] * R[1][u]
                 + rwm[r][2] * R[2][u];

#pragma unroll
    for (int r = 0; r < 3; r++) {
      float row[6];
#pragma unroll
      for (int j = 0; j < 6; j++)
        row[j] = cwm[j][0] * yi[r][0] + cwm[j][1] * yi[r][1]
               + cwm[j][2] * yi[r][2] + cwm[j][3] * yi[r][3]
               + cwm[j][4] * yi[r][4];
#pragma unroll
      for (int dj = 0; dj < 3; dj++) {
        const float a = wqc[r * 3 + dj];
#pragma unroll
        for (int j = 0; j < 4; j++) qo[cc][j] += a * row[j + dj];
      }
      if (r == 1) {
        up[cc][0] = row[1]; up[cc][1] = row[2];
        up[cc][2] = row[3]; up[cc][3] = row[4];
      }
    }
  }

  {
    h4 U;
    U.a = pack2(up[0][0], up[1][0]); U.b = pack2(up[0][1], up[1][1]);
    U.c = pack2(up[0][2], up[1][2]); U.d = pack2(up[0][3], up[1][3]);
    *(h4*)(lrup + ncp * HW + y * Wd + x) = U;
  }
  v2h* qr = qpad + ncp * QPLANE + (y + 1) * QRW + 1 + x;
#pragma unroll
  for (int j = 0; j < 4; j++) qr[j] = pack2(qo[0][j], qo[1][j]);

  if (x4 == 0) {
    kr[-2] = hz; kr[-1] = hz; vr[-2] = hz; vr[-1] = hz; qr[-1] = hz;
  }
  if (y == 0) {
    v2h* kz = kpad + ncp * KPLANE;
    v2h* vz = vpad + ncp * KPLANE;
    v2h* qz = qpad + ncp * QPLANE;
#pragma unroll
    for (int j = 0; j < 4; j++) {
      kz[2 + x + j] = hz;  kz[KRW + 2 + x + j] = hz;
      vz[2 + x + j] = hz;  vz[KRW + 2 + x + j] = hz;
      qz[1 + x + j] = hz;
    }
    if (x4 == 0) {
      kz[0] = hz; kz[1] = hz; kz[KRW] = hz; kz[KRW + 1] = hz;
      vz[0] = hz; vz[1] = hz; vz[KRW] = hz; vz[KRW + 1] = hz;
      qz[0] = hz;
    }
  }
  if (y == 127) {
    v2h* kz = kpad + ncp * KPLANE + 130 * KRW;
    v2h* vz = vpad + ncp * KPLANE + 130 * KRW;
    v2h* qz = qpad + ncp * QPLANE + 129 * QRW;
#pragma unroll
    for (int j = 0; j < 4; j++) {
      kz[2 + x + j] = hz;  kz[KRW + 2 + x + j] = hz;
      vz[2 + x + j] = hz;  vz[KRW + 2 + x + j] = hz;
      qz[1 + x + j] = hz;
    }
    if (x4 == 0) {
      kz[0] = hz; kz[1] = hz; kz[KRW] = hz; kz[KRW + 1] = hz;
      vz[0] = hz; vz[1] = hz; vz[KRW] = hz; vz[KRW + 1] = hz;
      qz[0] = hz;
    }
  }
  if (t < 256) zgapA[t] = hz;
  if (t < 4)   zgapB[t] = hz;
}

// ---- k_attn macros: load a K/V window set, accumulate sim, gating, value ----
#define DECLK(P, kp) \
  const f4p P##A0 = *(const f4p*)(kp); \
  const f4p P##A1 = *(const f4p*)((kp) + KRW); \
  const f4p P##A2 = *(const f4p*)((kp) + 2 * KRW); \
  const f4p P##A3 = *(const f4p*)((kp) + 3 * KRW); \
  const f4p P##A4 = *(const f4p*)((kp) + 4 * KRW); \
  const v2h P##b0 = (kp)[4]; \
  const v2h P##b1 = (kp)[KRW + 4]; \
  const v2h P##b2 = (kp)[2 * KRW + 4]; \
  const v2h P##b3 = (kp)[3 * KRW + 4]; \
  const v2h P##b4 = (kp)[4 * KRW + 4];

#define DECLQ(P, qp) \
  const f4p P##Q0 = *(const f4p*)(qp); \
  const f4p P##Q1 = *(const f4p*)((qp) + QRW); \
  const f4p P##Q2 = *(const f4p*)((qp) + 2 * QRW);

#define SIM25(P, qc) \
  sim[0]  = DOT2(qc, P##A0.a, sim[0]);  sim[1]  = DOT2(qc, P##A0.b, sim[1]); \
  sim[2]  = DOT2(qc, P##A0.c, sim[2]);  sim[3]  = DOT2(qc, P##A0.d, sim[3]); \
  sim[4]  = DOT2(qc, P##b0,   sim[4]); \
  sim[5]  = DOT2(qc, P##A1.a, sim[5]);  sim[6]  = DOT2(qc, P##A1.b, sim[6]); \
  sim[7]  = DOT2(qc, P##A1.c, sim[7]);  sim[8]  = DOT2(qc, P##A1.d, sim[8]); \
  sim[9]  = DOT2(qc, P##b1,   sim[9]); \
  sim[10] = DOT2(qc, P##A2.a, sim[10]); sim[11] = DOT2(qc, P##A2.b, sim[11]); \
  sim[12] = DOT2(qc, P##A2.c, sim[12]); sim[13] = DOT2(qc, P##A2.d, sim[13]); \
  sim[14] = DOT2(qc, P##b2,   sim[14]); \
  sim[15] = DOT2(qc, P##A3.a, sim[15]); sim[16] = DOT2(qc, P##A3.b, sim[16]); \
  sim[17] = DOT2(qc, P##A3.c, sim[17]); sim[18] = DOT2(qc, P##A3.d, sim[18]); \
  sim[19] = DOT2(qc, P##b3,   sim[19]); \
  sim[20] = DOT2(qc, P##A4.a, sim[20]); sim[21] = DOT2(qc, P##A4.b, sim[21]); \
  sim[22] = DOT2(qc, P##A4.c, sim[22]); sim[23] = DOT2(qc, P##A4.d, sim[23]); \
  sim[24] = DOT2(qc, P##b4,   sim[24]);

#define GATE(P, wp) { \
  const v2h q3_[9] = {P##Q0.a, P##Q0.b, P##Q0.c, P##Q1.a, P##Q1.b, P##Q1.c, \
                      P##Q2.a, P##Q2.b, P##Q2.c}; \
  const v2h k3_[9] = {P##A1.b, P##A1.c, P##A1.d, P##A2.b, P##A2.c, P##A2.d, \
                      P##A3.b, P##A3.c, P##A3.d}; \
  _Pragma("unroll") \
  for (int tp = 0; tp < 9; tp++) { \
    d0a = DOT2((wp)[tp],      q3_[tp], d0a); \
    d0a = DOT2((wp)[9 + tp],  k3_[tp], d0a); \
    d1a = DOT2((wp)[18 + tp], q3_[tp], d1a); \
    d1a = DOT2((wp)[27 + tp], k3_[tp], d1a); \
  } }

#define EPI(P, ci) { \
  v2h accA = wpk[0] * P##A0.a; \
  accA += wpk[1]  * P##A0.b;  accA += wpk[2]  * P##A0.c; \
  accA += wpk[3]  * P##A0.d;  accA += wpk[4]  * P##b0; \
  v2h accB = wpk[5] * P##A1.a; \
  accB += wpk[6]  * P##A1.b;  accB += wpk[7]  * P##A1.c; \
  accB += wpk[8]  * P##A1.d;  accB += wpk[9]  * P##b1; \
  accA += wpk[10] * P##A2.a;  accA += wpk[11] * P##A2.b; \
  accA += wpk[12] * P##A2.c;  accA += wpk[13] * P##A2.d; \
  accA += wpk[14] * P##b2; \
  accB += wpk[15] * P##A3.a;  accB += wpk[16] * P##A3.b; \
  accB += wpk[17] * P##A3.c;  accB += wpk[18] * P##A3.d; \
  accB += wpk[19] * P##b3; \
  accA += wpk[20] * P##A4.a;  accA += wpk[21] * P##A4.b; \
  accA += wpk[22] * P##A4.c;  accA += wpk[23] * P##A4.d; \
  accA += wpk[24] * P##b4; \
  const float acc0 = (float)accA.x + (float)accB.x; \
  const float acc1 = (float)accA.y + (float)accB.y; \
  const v2h vc = P##A2.c; \
  const v2h lu = lub[(ci) * HW]; \
  float* op = opb + (ci) * 2 * HW; \
  op[0]  = (float)lu.x + g0 * acc0 + g1 * (float)vc.x; \
  op[HW] = (float)lu.y + g0 * acc1 + g1 * (float)vc.y; }

// ---------------------------------------------------------------------------
// Kernel 2 (attention + gating): software-pipelined edition.
// k-pass: unroll-2, both K windows + Q issued before either set's dot2s
//   (wait count 8 -> 4, each overlapped with the sibling set's compute).
// v-pass: first two V windows issued BEFORE the softmax (independent of w);
//   softmax VALU hides their latency; remaining pairs unroll-2.
// __launch_bounds__(512,4) pins VGPR <= 128 (occupancy-cliff guard).
// grid (2,128,2) x 512.
// ---------------------------------------------------------------------------
__global__ __launch_bounds__(512, 4) void k_attn(
    const v2h* __restrict__ qpad, const v2h* __restrict__ kpad,
    const v2h* __restrict__ vpad, const v2h* __restrict__ lrup,
    const v2h* __restrict__ wah, const float* __restrict__ ba,
    float* __restrict__ outb)
{
  __shared__ float red[25 * 512];   // 51.2 KB
  __shared__ float dsh[2 * 512];    // 4 KB

  const int tid = threadIdx.x;
  const int px = tid & 63;
  const int cgu = __builtin_amdgcn_readfirstlane(tid >> 6);  // wave-uniform
  const int x = blockIdx.x * 64 + px;
  const int y = blockIdx.y;
  const int n = blockIdx.z;
  const int cp0 = cgu * 8;

  const v2h* kb = kpad + (n * CP + cp0) * KPLANE + y * KRW + x;
  const v2h* qb = qpad + (n * CP + cp0) * QPLANE + y * QRW + x;

  float sim[25];
#pragma unroll
  for (int k = 0; k < 25; k++) sim[k] = 0.f;
  float d0a = 0.f, d1a = 0.f;

#pragma unroll
  for (int cib = 0; cib < 8; cib += 2) {
    const v2h* kp0 = kb + cib * KPLANE;
    const v2h* kp1 = kp0 + KPLANE;
    const v2h* qp0 = qb + cib * QPLANE;
    const v2h* qp1 = qp0 + QPLANE;

    DECLK(S, kp0)               // set 0: K window
    DECLK(T, kp1)               // set 1: K window (in flight during set-0 math)
    DECLQ(S, qp0)

    const v2h qc0 = SQ1.b;
    SIM25(S, qc0)
    GATE(S, wah + (cp0 + cib) * 36)

    DECLQ(T, qp1)
    const v2h qc1 = TQ1.b;
    SIM25(T, qc1)
    GATE(T, wah + (cp0 + cib + 1) * 36)
  }

  // stash partials
#pragma unroll
  for (int k = 0; k < 25; k++) red[k * 512 + tid] = sim[k];
  dsh[tid] = d0a;
  dsh[512 + tid] = d1a;
  __syncthreads();

  // cross-wave reduce; slots 25,26 carry the gating sums
  for (int k = cgu; k < 27; k += 8) {
    if (k < 25) {
      float s = 0.f;
#pragma unroll
      for (int g = 0; g < 8; g++) s += red[k * 512 + g * 64 + px];
      red[k * 512 + px] = s;
    } else if (k == 25) {
      float s = 0.f;
#pragma unroll
      for (int g = 0; g < 8; g++) s += dsh[g * 64 + px];
      dsh[px] = s;
    } else {
      float s = 0.f;
#pragma unroll
      for (int g = 0; g < 8; g++) s += dsh[512 + g * 64 + px];
      dsh[512 + px] = s;
    }
  }
  __syncthreads();

  // issue first two V windows BEFORE softmax (independent of weights)
  const v2h* vb = vpad + (n * CP + cp0) * KPLANE + y * KRW + x;
  const v2h* lub = lrup + (n * CP + cp0) * HW + y * Wd + x;
  float* opb = outb + (n * C + 2 * cp0) * HW + y * Wd + x;

  DECLK(VA, vb)
  DECLK(VB, vb + KPLANE)

  // softmax + sigmoids in-register (overlaps the V loads above)
  float w[25];
  float m = -1e30f;
#pragma unroll
  for (int k = 0; k < 25; k++) { w[k] = red[k * 512 + px]; m = fmaxf(m, w[k]); }
  float tot = 0.f;
#pragma unroll
  for (int k = 0; k < 25; k++) { const float e = __expf(w[k] - m); w[k] = e; tot += e; }
  const float inv = __builtin_amdgcn_rcpf(tot);
  v2h wpk[25];
#pragma unroll
  for (int k = 0; k < 25; k++) {
    const float wf = w[k] * inv;
    wpk[k] = pack2(wf, wf);
  }
  const float g0 = __builtin_amdgcn_rcpf(1.f + __expf(-(dsh[px] + ba[0])));
  const float g1 = __builtin_amdgcn_rcpf(1.f + __expf(-(dsh[512 + px] + ba[1])));

  EPI(VA, 0)
  EPI(VB, 1)

#pragma unroll
  for (int cib = 2; cib < 8; cib += 2) {
    DECLK(VC, vb + cib * KPLANE)
    DECLK(VD, vb + (cib + 1) * KPLANE)
    EPI(VC, cib)
    EPI(VD, cib + 1)
  }
}

// ---------------------------------------------------------------------------
extern "C" void kernel_launch(void* const* d_in, const int* in_sizes, int n_in,
                              void* d_out, int out_size, void* d_ws,
                              size_t ws_size, hipStream_t stream)
{
  const float* hr = (const float*)d_in[0];
  const float* lr = (const float*)d_in[1];
  const float* wq = (const float*)d_in[2];
  const float* bq = (const float*)d_in[3];
  const float* wk = (const float*)d_in[4];
  const float* bk = (const float*)d_in[5];
  const float* wv = (const float*)d_in[6];
  const float* bv = (const float*)d_in[7];
  const float* wa = (const float*)d_in[8];
  const float* ba = (const float*)d_in[9];

  float* out = (float*)d_out;
  v2h* ws2 = (v2h*)d_ws;

  // layout (h2 elems): kpad | vpad | qpad | zgapA(256) | lrup | zgapB(4) | wah
  v2h* kpad  = ws2;
  v2h* vpad  = kpad + KSZ;
  v2h* qpad  = vpad + KSZ;
  v2h* zgapA = qpad + QSZ;
  v2h* lrupb = zgapA + 256;
  v2h* zgapB = lrupb + LSZ;
  v2h* wahb  = zgapB + 4;

  k_pre<<<dim3(2048), dim3(256), 0, stream>>>(
      hr, lr, wq, bq, wk, bk, wv, bv, wa,
      qpad, kpad, vpad, lrupb, zgapA, zgapB, wahb);
  k_attn<<<dim3(2, 128, 2), dim3(512), 0, stream>>>(
      qpad, kpad, vpad, lrupb, wahb, ba, out);
}